// Round 13
// baseline (773.306 us; speedup 1.0000x reference)
//
#include <hip/hip_runtime.h>
#include <math.h>

#define T_TRI 20000
#define KNN_K 20
#define H     128
#define GRES  16
#define NCELL (GRES*GRES*GRES)

// ---------------- workspace layout (bytes) ----------------
#define WS_GEO    0                       // 960KB (original-space geo)
#define WS_BQ     (1u<<20)                // 320KB
#define WS_NBR    (2u<<20)                // 1.6MB (sorted-space neighbor lists)
#define WS_RS     (4u<<20)                // 512B
#define WS_WT     ((4u<<20)+4096)         // 320KB
#define WS_MM     (5u<<20)                // 64B
#define WS_HIST   ((5u<<20)+(4u<<10))    // 16KB
#define WS_CSTART ((5u<<20)+(256u<<10))  // 16KB+8
#define WS_CPTR   ((5u<<20)+(512u<<10))  // 16KB
#define WS_CID    ((5u<<20)+(768u<<10))  // 80KB
#define WS_CSORT  ((5u<<20)+(896u<<10))  // 80KB
#define WS_OID    (6u<<20)               // 80KB
#define WS_BQS    ((6u<<20)+(128u<<10))  // 320KB
#define WS_PS     ((6u<<20)+(512u<<10))  // 80KB (probs_s)
#define WS_GEOS   (7u<<20)               // 960KB (sorted-space geo)
#define WS_X      (9u<<20)
#define WS_Y      (20u<<20)

__device__ __forceinline__ float readlane_f(float v, int l) {
    return __uint_as_float(__builtin_amdgcn_readlane(__float_as_uint(v), l));
}
// order-preserving float<->uint (for atomicMin/Max on floats)
__device__ __forceinline__ unsigned encf(float f) {
    unsigned u = __float_as_uint(f);
    return (u & 0x80000000u) ? ~u : (u | 0x80000000u);
}
__device__ __forceinline__ float decf(unsigned e) {
    unsigned u = (e & 0x80000000u) ? (e & 0x7FFFFFFFu) : ~e;
    return __uint_as_float(u);
}

// ---------------- init: zero histogram, minmax sentinels ----------------
__global__ void grid_init_kernel(unsigned* __restrict__ hist, unsigned* __restrict__ mm) {
    int i = blockIdx.x * 256 + threadIdx.x;
    if (i < NCELL) hist[i] = 0u;
    if (i < 3) mm[i] = 0xFFFFFFFFu;          // mins (uint-encoded)
    if (i >= 3 && i < 6) mm[i] = 0u;         // maxs
}

// ---------------- geometry (+ bary AABB via wave-reduced atomics) ----------------
__global__ void geom_kernel(const float* __restrict__ pts, const int* __restrict__ tris,
                            float* __restrict__ geo, float4* __restrict__ bq,
                            unsigned* __restrict__ mm) {
    int t = blockIdx.x * blockDim.x + threadIdx.x;
    int lane = threadIdx.x & 63;
    bool act = (t < T_TRI);
    int tt = act ? t : 0;
    int i0 = tris[3*tt], i1 = tris[3*tt+1], i2 = tris[3*tt+2];
    float ax = pts[3*i0], ay = pts[3*i0+1], az = pts[3*i0+2];
    float bx = pts[3*i1], by = pts[3*i1+1], bz = pts[3*i1+2];
    float cx = pts[3*i2], cy = pts[3*i2+1], cz = pts[3*i2+2];
    float e0x = ax-bx, e0y = ay-by, e0z = az-bz;   // e_ij
    float e1x = ax-cx, e1y = ay-cy, e1z = az-cz;   // e_ik
    float e2x = bx-cx, e2y = by-cy, e2z = bz-cz;   // e_jk
    float mnx = fminf(fminf(e0x,e1x),e2x), mny = fminf(fminf(e0y,e1y),e2y), mnz = fminf(fminf(e0z,e1z),e2z);
    float mxx = fmaxf(fmaxf(e0x,e1x),e2x), mxy = fmaxf(fmaxf(e0y,e1y),e2y), mxz = fmaxf(fmaxf(e0z,e1z),e2z);
    float gx = (ax+bx+cx)*(1.0f/3.0f), gy = (ay+by+cy)*(1.0f/3.0f), gz = (az+bz+cz)*(1.0f/3.0f);
    float sq = (gx*gx + gy*gy) + gz*gz;
    if (act) {
        float* g = geo + (size_t)t*12;
        g[0]=mnx; g[1]=mny; g[2]=mnz; g[3]=mxx; g[4]=mxy; g[5]=mxz;
        g[6]=gx;  g[7]=gy;  g[8]=gz;  g[9]=0.f; g[10]=0.f; g[11]=0.f;
        bq[t] = make_float4(gx, gy, gz, sq);
    }
    unsigned n0 = act ? encf(gx) : 0xFFFFFFFFu;
    unsigned n1 = act ? encf(gy) : 0xFFFFFFFFu;
    unsigned n2 = act ? encf(gz) : 0xFFFFFFFFu;
    unsigned x0 = act ? encf(gx) : 0u;
    unsigned x1 = act ? encf(gy) : 0u;
    unsigned x2 = act ? encf(gz) : 0u;
#pragma unroll
    for (int off = 32; off >= 1; off >>= 1) {
        n0 = min(n0, (unsigned)__shfl_xor((int)n0, off));
        n1 = min(n1, (unsigned)__shfl_xor((int)n1, off));
        n2 = min(n2, (unsigned)__shfl_xor((int)n2, off));
        x0 = max(x0, (unsigned)__shfl_xor((int)x0, off));
        x1 = max(x1, (unsigned)__shfl_xor((int)x1, off));
        x2 = max(x2, (unsigned)__shfl_xor((int)x2, off));
    }
    if (lane == 0) {
        atomicMin(&mm[0], n0); atomicMin(&mm[1], n1); atomicMin(&mm[2], n2);
        atomicMax(&mm[3], x0); atomicMax(&mm[4], x1); atomicMax(&mm[5], x2);
    }
}

// ---------------- cell assignment + histogram (16^3) ----------------
__global__ void cellhist_kernel(const float4* __restrict__ bq, const unsigned* __restrict__ mm,
                                int* __restrict__ cellid, unsigned* __restrict__ hist) {
    int t = blockIdx.x * 256 + threadIdx.x;
    if (t >= T_TRI) return;
    float mnx = decf(mm[0]), mny = decf(mm[1]), mnz = decf(mm[2]);
    float mxx = decf(mm[3]), mxy = decf(mm[4]), mxz = decf(mm[5]);
    float ihx = (float)GRES / fmaxf(mxx-mnx, 1e-30f);
    float ihy = (float)GRES / fmaxf(mxy-mny, 1e-30f);
    float ihz = (float)GRES / fmaxf(mxz-mnz, 1e-30f);
    float4 b = bq[t];
    int ix = min(GRES-1, max(0, (int)((b.x-mnx)*ihx)));
    int iy = min(GRES-1, max(0, (int)((b.y-mny)*ihy)));
    int iz = min(GRES-1, max(0, (int)((b.z-mnz)*ihz)));
    int c = (ix<<8) | (iy<<4) | iz;
    cellid[t] = c;
    atomicAdd(&hist[c], 1u);
}

// ---------------- exclusive prefix over 4096 cells (1 block) ----------------
__global__ __launch_bounds__(1024) void prefix_kernel(const unsigned* __restrict__ hist,
                                                      unsigned* __restrict__ cellstart,
                                                      unsigned* __restrict__ cellptr) {
    __shared__ unsigned sbuf[1024];
    int tid = threadIdx.x;
    uint4 v = ((const uint4*)hist)[tid];
    unsigned mysum = v.x + v.y + v.z + v.w;
    sbuf[tid] = mysum;
    __syncthreads();
    for (int off = 1; off < 1024; off <<= 1) {
        unsigned add = (tid >= off) ? sbuf[tid - off] : 0u;
        __syncthreads();
        sbuf[tid] += add;
        __syncthreads();
    }
    unsigned excl = sbuf[tid] - mysum;
    unsigned p0 = excl, p1 = p0 + v.x, p2 = p1 + v.y, p3 = p2 + v.z;
    cellstart[4*tid+0] = p0; cellstart[4*tid+1] = p1;
    cellstart[4*tid+2] = p2; cellstart[4*tid+3] = p3;
    cellptr[4*tid+0] = p0; cellptr[4*tid+1] = p1;
    cellptr[4*tid+2] = p2; cellptr[4*tid+3] = p3;
    if (tid == 1023) cellstart[NCELL] = p3 + v.w;
}

// ---------------- scatter into cell-sorted order (+ relabeled geo/probs) ----------------
__global__ void scatter_kernel(const float4* __restrict__ bq, const int* __restrict__ cellid,
                               const float* __restrict__ geo, const float* __restrict__ probs,
                               unsigned* __restrict__ cellptr, float4* __restrict__ bqs,
                               int* __restrict__ oid, int* __restrict__ csort,
                               float* __restrict__ geo_s, float* __restrict__ probs_s) {
    int t = blockIdx.x * 256 + threadIdx.x;
    if (t >= T_TRI) return;
    int c = cellid[t];
    unsigned p = atomicAdd(&cellptr[c], 1u);
    bqs[p] = bq[t];
    oid[p]  = t;
    csort[p] = c;
    const float4* g4 = (const float4*)geo;
    float4* g4s = (float4*)geo_s;
    g4s[(size_t)p*3+0] = g4[(size_t)t*3+0];
    g4s[(size_t)p*3+1] = g4[(size_t)t*3+1];
    g4s[(size_t)p*3+2] = g4[(size_t)t*3+2];
    probs_s[p] = probs[t];
}

// ---------------- grid KNN: 2 rows/wave, z-column ranges, exact pruning ----------------
// One wave serves 2 sorted-adjacent rows (usually same cell): union box =
// componentwise span of the 2 cells. w=1 scans the full box+1 via COLUMN
// ranges (cells lexicographic in (ix,iy,iz) -> a column's z-span is ONE
// contiguous candidate range; 9 drains instead of 27, coalesced batches).
// w>=2 (rare: only rows with d21 > w*hmin) scans ring(w)=box(w)\box(w-1)
// per-cell. Stop after w iff both th < (w*hmin-1e-3)^2: unscanned cells are
// >= w+1 cell-indices away from both rows' cells -> true distance >= w*hmin;
// the 1e-3 slack dwarfs the ~1e-6 formula error (R11-proven argument).
// Distance formula, insert/drain logic, tie-break on ORIGINAL index, and the
// sorted-index payload are byte-identical to the R11/R12-passing kernels.
__global__ __launch_bounds__(256) void knn_grid_kernel(const float4* __restrict__ bqs,
        const int* __restrict__ oid, const int* __restrict__ csort,
        const unsigned* __restrict__ cellstart, const unsigned* __restrict__ mm,
        int* __restrict__ nbr) {
    int wave = threadIdx.x >> 6, lane = threadIdx.x & 63;
    int r0 = blockIdx.x * 8 + wave * 2;
    int r1 = r0 + 1;
    float4 q0 = bqs[r0], q1 = bqs[r1];
    int c0 = csort[r0], c1 = csort[r1];
    int c0x=(c0>>8)&15, c0y=(c0>>4)&15, c0z=c0&15;
    int c1x=(c1>>8)&15, c1y=(c1>>4)&15, c1z=c1&15;
    int bx0=min(c0x,c1x), bx1=max(c0x,c1x);
    int by0=min(c0y,c1y), by1=max(c0y,c1y);
    int bz0=min(c0z,c1z), bz1=max(c0z,c1z);
    float hx = (decf(mm[3])-decf(mm[0]))*(1.f/GRES);
    float hy = (decf(mm[4])-decf(mm[1]))*(1.f/GRES);
    float hz = (decf(mm[5])-decf(mm[2]))*(1.f/GRES);
    float hmin = fminf(hx, fminf(hy, hz));

    float rd0 = INFINITY, rd1 = INFINITY;
    int   ri0 = 0x7FF00000 | lane, ri1 = ri0;   // distinct sentinels (orig-idx key)
    int   rk0 = lane, rk1 = lane;               // sorted-idx payload
    float th0 = INFINITY, th1 = INFINITY;
    int   mi0 = 0x7FFFFFFF, mi1 = 0x7FFFFFFF;

#define DRAIN(R)                                                                 \
    {                                                                            \
        unsigned long long bal = __ballot(kv && (d##R <= th##R));                \
        while (bal) {                                                            \
            int src = __ffsll(bal) - 1; bal &= bal - 1;                          \
            float dc = readlane_f(d##R, src);                                    \
            int jc = __builtin_amdgcn_readlane(ov, src);                         \
            int kc = (int)base + src;                                            \
            if ((dc < th##R) || (dc == th##R && jc < mi##R)) {                   \
                bool less = (rd##R < dc) || (rd##R == dc && ri##R < jc);         \
                int pos = __popcll(__ballot(less) & 0x1FFFFFull);                \
                float sd = __shfl_up(rd##R, 1);                                  \
                int si = __shfl_up(ri##R, 1);                                    \
                int sk = __shfl_up(rk##R, 1);                                    \
                if (lane < 21) {                                                 \
                    if (lane == pos)      { rd##R = dc; ri##R = jc; rk##R = kc; }\
                    else if (lane > pos)  { rd##R = sd; ri##R = si; rk##R = sk; }\
                }                                                                \
                th##R = readlane_f(rd##R, 20);                                   \
                mi##R = __builtin_amdgcn_readlane(ri##R, 20);                    \
            }                                                                    \
        }                                                                        \
    }

#define SCAN_RANGE(RS, RE)                                                       \
    for (unsigned base = (RS); base < (RE); base += 64u) {                       \
        unsigned k = base + (unsigned)lane;                                      \
        bool kv = (k < (RE));                                                    \
        float4 c4 = kv ? bqs[k] : make_float4(INFINITY,INFINITY,INFINITY,INFINITY); \
        int ov = kv ? oid[k] : 0x7FFFFFFF;                                       \
        float dt0 = fmaf(q0.z, c4.z, fmaf(q0.y, c4.y, q0.x*c4.x));               \
        float d0 = (q0.w + c4.w) - 2.0f*dt0;                                     \
        float dt1 = fmaf(q1.z, c4.z, fmaf(q1.y, c4.y, q1.x*c4.x));               \
        float d1 = (q1.w + c4.w) - 2.0f*dt1;                                     \
        DRAIN(0)                                                                 \
        DRAIN(1)                                                                 \
    }

    for (int w = 1; w < GRES; ++w) {
        int X0 = max(bx0-w, 0), X1 = min(bx1+w, GRES-1);
        int Y0 = max(by0-w, 0), Y1 = min(by1+w, GRES-1);
        int Z0 = max(bz0-w, 0), Z1 = min(bz1+w, GRES-1);
        if (w == 1) {
            int Wy = Y1 - Y0 + 1;
            int ncol = (X1 - X0 + 1) * Wy;
            for (int ib = 0; ib < ncol; ib += 64) {
                int i = ib + lane;
                bool val = (i < ncol);
                int ii = val ? i : 0;
                int ex = X0 + ii / Wy, ey = Y0 + ii % Wy;
                int colb = (ex<<8) | (ey<<4);
                unsigned cs = 0u, ce = 0u;
                if (val) { cs = cellstart[colb + Z0]; ce = cellstart[colb + Z1 + 1]; }
                val = val && (cs < ce);
                unsigned long long cm = __ballot(val);
                if (ib == 0) {   // center-column-first: tighten theta early (perf only)
                    int j0 = (c0x - X0)*Wy + (c0y - Y0);
                    if (j0 < 64 && ((cm >> j0) & 1ull)) {
                        unsigned s0 = (unsigned)__builtin_amdgcn_readlane((int)cs, j0);
                        unsigned e0 = (unsigned)__builtin_amdgcn_readlane((int)ce, j0);
                        SCAN_RANGE(s0, e0)
                        cm &= ~(1ull << j0);
                    }
                }
                while (cm) {
                    int cl = __ffsll(cm) - 1; cm &= cm - 1;
                    unsigned s0 = (unsigned)__builtin_amdgcn_readlane((int)cs, cl);
                    unsigned e0 = (unsigned)__builtin_amdgcn_readlane((int)ce, cl);
                    SCAN_RANGE(s0, e0)
                }
            }
        } else {
            // ring(w) = box(w) \ box(w-1), per-cell (rare path)
            int WX = (bx1-bx0+1) + 2*w, WY = (by1-by0+1) + 2*w, WZ = (bz1-bz0+1) + 2*w;
            int tot = WX * WY * WZ;
            for (int ib = 0; ib < tot; ib += 64) {
                int i = ib + lane;
                bool val = (i < tot);
                int ii = val ? i : 0;
                int ez = ii % WZ; int rem = ii / WZ;
                int ey = rem % WY; int ex = rem / WY;
                ex += bx0 - w; ey += by0 - w; ez += bz0 - w;
                int dxs = max(max(bx0-ex, ex-bx1), 0);
                int dys = max(max(by0-ey, ey-by1), 0);
                int dzs = max(max(bz0-ez, ez-bz1), 0);
                int cheb = max(dxs, max(dys, dzs));
                val = val && (cheb == w);
                val = val && ex >= 0 && ex < GRES && ey >= 0 && ey < GRES && ez >= 0 && ez < GRES;
                int cell = (ex<<8) | (ey<<4) | ez;
                unsigned cs = 0u, ce = 0u;
                if (val) { cs = cellstart[cell]; ce = cellstart[cell+1]; }
                val = val && (cs < ce);
                unsigned long long cm = __ballot(val);
                while (cm) {
                    int cl = __ffsll(cm) - 1; cm &= cm - 1;
                    unsigned s0 = (unsigned)__builtin_amdgcn_readlane((int)cs, cl);
                    unsigned e0 = (unsigned)__builtin_amdgcn_readlane((int)ce, cl);
                    SCAN_RANGE(s0, e0)
                }
            }
        }
        bool cov = (X0 == 0 && X1 == GRES-1 && Y0 == 0 && Y1 == GRES-1 && Z0 == 0 && Z1 == GRES-1);
        if (cov) break;
        float bd = (float)w * hmin - 1e-3f;
        if (bd > 0.f && th0 < bd*bd && th1 < bd*bd) break;
    }
#undef SCAN_RANGE
#undef DRAIN
    // lane l holds rank-l entry; rank 0 = self, dropped; emit SORTED index
    if (lane >= 1 && lane < 21) {
        nbr[r0*KNN_K + lane - 1] = rk0;
        nbr[r1*KNN_K + lane - 1] = rk1;
    }
}

// ---------------- layer-0 helpers (sorted space) ----------------
__global__ void rowsum_kernel(const float* __restrict__ W1, float* __restrict__ rs) {
    int f = threadIdx.x;
    float s = 0.f;
    for (int c = 0; c < H; ++c) s += W1[f*137 + 9 + c];
    rs[f] = s;
}
__global__ void y0_kernel(const float* __restrict__ ps, const float* __restrict__ rs, float* __restrict__ Y) {
    int tid = blockIdx.x * blockDim.x + threadIdx.x;   // over T*H
    int t = tid >> 7, f = tid & 127;
    Y[tid] = ps[t] * rs[f];
}

// ---------------- weight pre-transpose (once, tiny) ----------------
__global__ void wtrans_kernel(const float* __restrict__ W11, const float* __restrict__ W12,
                              const float* __restrict__ W20, const float* __restrict__ W21,
                              const float* __restrict__ W22, float* __restrict__ WTg) {
    int f = threadIdx.x, c = blockIdx.x, m = blockIdx.y;
    const float* W; int stride, col0;
    if      (m == 0) { W = W11; stride = 137; col0 = 9; }
    else if (m == 1) { W = W12; stride = 137; col0 = 9; }
    else if (m == 2) { W = W20; stride = 128; col0 = 0; }
    else if (m == 3) { W = W21; stride = 128; col0 = 0; }
    else             { W = W22; stride = 128; col0 = 0; }
    WTg[m*16384 + (c>>2)*512 + f*4 + (c&3)] = W[f*stride + col0 + c];
}

// ---------------- standalone dense (sorted space): Y_s = X_s@W1b^T ----------------
#define DTPB 16
__global__ __launch_bounds__(128) void dense_kernel(const float* __restrict__ A, const float* __restrict__ WTg,
                             float* __restrict__ C) {
    __shared__ float Ar[8][128];
    int f = threadIdx.x;
    int t0 = blockIdx.x * DTPB;
    for (int tt = 0; tt < DTPB; tt += 8) {
        __syncthreads();
#pragma unroll
        for (int j = 0; j < 8; ++j) Ar[j][f] = A[(size_t)(t0+tt+j)*H + f];
        __syncthreads();
        float a0 = 0.f, a1 = 0.f, a2 = 0.f, a3 = 0.f;
        float a4_ = 0.f, a5 = 0.f, a6 = 0.f, a7 = 0.f;
#pragma unroll
        for (int c4 = 0; c4 < 32; ++c4) {
            float4 w = *(const float4*)&WTg[c4*512 + f*4];
#define DROW(J, ACC)                                                        \
            {                                                               \
                float4 v = ((const float4*)Ar[J])[c4];                      \
                ACC = fmaf(w.x, v.x, ACC); ACC = fmaf(w.y, v.y, ACC);       \
                ACC = fmaf(w.z, v.z, ACC); ACC = fmaf(w.w, v.w, ACC);       \
            }
            DROW(0, a0) DROW(1, a1) DROW(2, a2) DROW(3, a3)
            DROW(4, a4_) DROW(5, a5) DROW(6, a6) DROW(7, a7)
#undef DROW
        }
        C[(size_t)(t0+tt+0)*H + f] = a0;
        C[(size_t)(t0+tt+1)*H + f] = a1;
        C[(size_t)(t0+tt+2)*H + f] = a2;
        C[(size_t)(t0+tt+3)*H + f] = a3;
        C[(size_t)(t0+tt+4)*H + f] = a4_;
        C[(size_t)(t0+tt+5)*H + f] = a5;
        C[(size_t)(t0+tt+6)*H + f] = a6;
        C[(size_t)(t0+tt+7)*H + f] = a7;
    }
}

// ---------------- fused edge + W2 (+ head), sorted space — unchanged (R12 pass) ----------------
__global__ __launch_bounds__(256) void edgefused_kernel(const float* __restrict__ Y, const float* __restrict__ geo_s,
                            const int* __restrict__ nbr, const float* __restrict__ W1,
                            const float* __restrict__ b1, const float* __restrict__ WTg,
                            const float* __restrict__ b2, float* __restrict__ X,
                            const float* __restrict__ Wf, const float* __restrict__ bf,
                            float* __restrict__ out, const int* __restrict__ oid, int last) {
    __shared__ float W1aT[9][128];
    __shared__ float Srow[4][128];
    __shared__ float fpart[4][2];
    for (int idx = threadIdx.x; idx < 9*128; idx += 256) {
        int c = idx >> 7, ff = idx & 127;
        W1aT[c][ff] = W1[ff*137 + c];
    }
    __syncthreads();
    int wave = threadIdx.x >> 6, lane = threadIdx.x & 63;
    int t0b = blockIdx.x * 4;
    {
        int t = t0b + wave;
        float wlo[9], whi[9];
#pragma unroll
        for (int c = 0; c < 9; ++c) { wlo[c] = W1aT[c][lane]; whi[c] = W1aT[c][64+lane]; }
        const float4* g4 = (const float4*)geo_s;
        float4 s0 = g4[t*3+0], s1 = g4[t*3+1], s2 = g4[t*3+2];
        float b1lo = b1[lane],            b1hi = b1[64+lane];
        float ylo  = Y[(size_t)t*H+lane], yhi  = Y[(size_t)t*H+64+lane];
        float accLo = 0.f, accHi = 0.f;
#pragma unroll
        for (int e = 0; e < KNN_K; ++e) {
            int tg = nbr[t*KNN_K + e];
            float4 t0 = g4[tg*3+0], t1 = g4[tg*3+1], t2 = g4[tg*3+2];
            float r0 = s0.x-t0.x, r1 = s0.y-t0.y, r2 = s0.z-t0.z, r3 = s0.w-t0.w;
            float r4 = s1.x-t1.x, r5 = s1.y-t1.y, r6 = s1.z-t1.z, r7 = s1.w-t1.w;
            float r8 = s2.x-t2.x;
            float gLo = b1lo;
            gLo = fmaf(wlo[0], r0, gLo); gLo = fmaf(wlo[1], r1, gLo); gLo = fmaf(wlo[2], r2, gLo);
            gLo = fmaf(wlo[3], r3, gLo); gLo = fmaf(wlo[4], r4, gLo);
            gLo = fmaf(wlo[5], r5, gLo); gLo = fmaf(wlo[6], r6, gLo);
            gLo = fmaf(wlo[7], r7, gLo); gLo = fmaf(wlo[8], r8, gLo);
            float gHi = b1hi;
            gHi = fmaf(whi[0], r0, gHi); gHi = fmaf(whi[1], r1, gHi); gHi = fmaf(whi[2], r2, gHi);
            gHi = fmaf(whi[3], r3, gHi); gHi = fmaf(whi[4], r4, gHi);
            gHi = fmaf(whi[5], r5, gHi); gHi = fmaf(whi[6], r6, gHi);
            gHi = fmaf(whi[7], r7, gHi); gHi = fmaf(whi[8], r8, gHi);
            accLo += fmaxf(gLo + ylo - Y[(size_t)tg*H + lane], 0.f);
            accHi += fmaxf(gHi + yhi - Y[(size_t)tg*H + 64 + lane], 0.f);
        }
        Srow[wave][lane]    = accLo;
        Srow[wave][64+lane] = accHi;
    }
    __syncthreads();
    int f = threadIdx.x & 127, half = threadIdx.x >> 7;
    float base = b2[f] * (float)KNN_K;
    float a0 = base, a1 = base;
    const int r0_ = half * 2;
#pragma unroll
    for (int c4 = 0; c4 < 32; ++c4) {
        float4 w = *(const float4*)&WTg[c4*512 + f*4];
        float4 v0 = ((const float4*)Srow[r0_+0])[c4];
        float4 v1 = ((const float4*)Srow[r0_+1])[c4];
        a0 = fmaf(w.x, v0.x, a0); a0 = fmaf(w.y, v0.y, a0);
        a0 = fmaf(w.z, v0.z, a0); a0 = fmaf(w.w, v0.w, a0);
        a1 = fmaf(w.x, v1.x, a1); a1 = fmaf(w.y, v1.y, a1);
        a1 = fmaf(w.z, v1.z, a1); a1 = fmaf(w.w, v1.w, a1);
    }
    if (!last) {
        X[(size_t)(t0b+r0_+0)*H + f] = a0;
        X[(size_t)(t0b+r0_+1)*H + f] = a1;
    } else {
        float wf = Wf[f];
        float p0 = a0*wf, p1 = a1*wf;
#pragma unroll
        for (int off = 32; off >= 1; off >>= 1) {
            p0 += __shfl_xor(p0, off);
            p1 += __shfl_xor(p1, off);
        }
        if (lane == 0) { fpart[wave][0] = p0; fpart[wave][1] = p1; }
        __syncthreads();
        if (threadIdx.x < 4) {
            int rr = threadIdx.x;
            int h = rr >> 1, j = rr & 1;
            float z = fpart[2*h][j] + fpart[2*h+1][j] + bf[0];
            out[oid[t0b + h*2 + j]] = 1.0f / (1.0f + expf(-z));
        }
    }
}

extern "C" void kernel_launch(void* const* d_in, const int* in_sizes, int n_in,
                              void* d_out, int out_size, void* d_ws, size_t ws_size,
                              hipStream_t stream) {
    (void)in_sizes; (void)n_in; (void)out_size; (void)ws_size;
    const float* pts   = (const float*)d_in[0];
    const int*   tris  = (const int*)d_in[1];
    const float* probs = (const float*)d_in[2];
    const float* W1[3] = {(const float*)d_in[3],  (const float*)d_in[7],  (const float*)d_in[11]};
    const float* b1[3] = {(const float*)d_in[4],  (const float*)d_in[8],  (const float*)d_in[12]};
    const float* W2[3] = {(const float*)d_in[5],  (const float*)d_in[9],  (const float*)d_in[13]};
    const float* b2[3] = {(const float*)d_in[6],  (const float*)d_in[10], (const float*)d_in[14]};
    const float* Wf = (const float*)d_in[15];
    const float* bf = (const float*)d_in[16];
    float* out = (float*)d_out;

    char* ws = (char*)d_ws;
    float*    geo  = (float*)(ws + WS_GEO);
    float4*   bq   = (float4*)(ws + WS_BQ);
    int*      nbr  = (int*)(ws + WS_NBR);
    float*    rs   = (float*)(ws + WS_RS);
    float*    WTg  = (float*)(ws + WS_WT);
    unsigned* mm   = (unsigned*)(ws + WS_MM);
    unsigned* hist = (unsigned*)(ws + WS_HIST);
    unsigned* cst  = (unsigned*)(ws + WS_CSTART);
    unsigned* cptr = (unsigned*)(ws + WS_CPTR);
    int*      cid  = (int*)(ws + WS_CID);
    int*      cso  = (int*)(ws + WS_CSORT);
    int*      oid  = (int*)(ws + WS_OID);
    float4*   bqs  = (float4*)(ws + WS_BQS);
    float*    ps   = (float*)(ws + WS_PS);
    float*    geos = (float*)(ws + WS_GEOS);
    float*    X    = (float*)(ws + WS_X);
    float*    Y    = (float*)(ws + WS_Y);

    grid_init_kernel<<<NCELL/256, 256, 0, stream>>>(hist, mm);
    geom_kernel<<<(T_TRI+255)/256, 256, 0, stream>>>(pts, tris, geo, bq, mm);
    cellhist_kernel<<<(T_TRI+255)/256, 256, 0, stream>>>(bq, mm, cid, hist);
    prefix_kernel<<<1, 1024, 0, stream>>>(hist, cst, cptr);
    scatter_kernel<<<(T_TRI+255)/256, 256, 0, stream>>>(bq, cid, geo, probs, cptr, bqs, oid, cso, geos, ps);
    knn_grid_kernel<<<T_TRI/8, 256, 0, stream>>>(bqs, oid, cso, cst, mm, nbr);
    rowsum_kernel<<<1, 128, 0, stream>>>(W1[0], rs);
    wtrans_kernel<<<dim3(128,5), 128, 0, stream>>>(W1[1], W1[2], W2[0], W2[1], W2[2], WTg);
    y0_kernel<<<(T_TRI*H)/256, 256, 0, stream>>>(ps, rs, Y);
    for (int l = 0; l < 3; ++l) {
        if (l > 0)
            dense_kernel<<<T_TRI/DTPB, 128, 0, stream>>>(X, WTg + (size_t)(l-1)*16384, Y);
        edgefused_kernel<<<T_TRI/4, 256, 0, stream>>>(Y, geos, nbr, W1[l], b1[l],
                                                      WTg + (size_t)(2+l)*16384, b2[l], X,
                                                      Wf, bf, out, oid, (l == 2) ? 1 : 0);
    }
}

// Round 14
// 474.579 us; speedup vs baseline: 1.6295x; 1.6295x over previous
//
#include <hip/hip_runtime.h>
#include <math.h>

#define T_TRI 20000
#define KNN_K 20
#define H     128

// ---------------- workspace layout (bytes) ----------------
#define WS_GEO   0
#define WS_BQ    (1u<<20)
#define WS_NBR   (2u<<20)
#define WS_RS    (4u<<20)              // rs: 512B
#define WS_WT    ((4u<<20)+4096)       // 5 transposed weights, 320KB
#define WS_MM    (5u<<20)              // minmax: 6 u32
#define WS_CSTART ((5u<<20)+64)        // 4097 u32
#define WS_CPTR  ((5u<<20)+(32u<<10))  // 4096 u32
#define WS_HIST  ((5u<<20)+(64u<<10))  // 4096 u32
#define WS_CID   ((5u<<20)+(128u<<10)) // 20000 i32
#define WS_CSORT ((5u<<20)+(256u<<10)) // 20000 i32
#define WS_OID   ((5u<<20)+(384u<<10)) // 20000 i32
#define WS_BQS   ((5u<<20)+(512u<<10)) // 20000 float4
#define WS_X     (6u<<20)
#define WS_Y     (17u<<20)

__device__ __forceinline__ float readlane_f(float v, int l) {
    return __uint_as_float(__builtin_amdgcn_readlane(__float_as_uint(v), l));
}
// order-preserving float<->uint (for atomicMin/Max on floats)
__device__ __forceinline__ unsigned encf(float f) {
    unsigned u = __float_as_uint(f);
    return (u & 0x80000000u) ? ~u : (u | 0x80000000u);
}
__device__ __forceinline__ float decf(unsigned e) {
    unsigned u = (e & 0x80000000u) ? (e & 0x7FFFFFFFu) : ~e;
    return __uint_as_float(u);
}

// ---------------- init: zero histogram, minmax sentinels ----------------
__global__ void grid_init_kernel(unsigned* __restrict__ hist, unsigned* __restrict__ mm) {
    int i = blockIdx.x * 256 + threadIdx.x;
    if (i < 4096) hist[i] = 0u;
    if (i < 3) mm[i] = 0xFFFFFFFFu;          // mins (uint-encoded)
    if (i >= 3 && i < 6) mm[i] = 0u;         // maxs
}

// ---------------- geometry (+ bary AABB via wave-reduced atomics) ----------------
__global__ void geom_kernel(const float* __restrict__ pts, const int* __restrict__ tris,
                            float* __restrict__ geo, float4* __restrict__ bq,
                            unsigned* __restrict__ mm) {
    int t = blockIdx.x * blockDim.x + threadIdx.x;
    int lane = threadIdx.x & 63;
    bool act = (t < T_TRI);
    int tt = act ? t : 0;
    int i0 = tris[3*tt], i1 = tris[3*tt+1], i2 = tris[3*tt+2];
    float ax = pts[3*i0], ay = pts[3*i0+1], az = pts[3*i0+2];
    float bx = pts[3*i1], by = pts[3*i1+1], bz = pts[3*i1+2];
    float cx = pts[3*i2], cy = pts[3*i2+1], cz = pts[3*i2+2];
    float e0x = ax-bx, e0y = ay-by, e0z = az-bz;   // e_ij
    float e1x = ax-cx, e1y = ay-cy, e1z = az-cz;   // e_ik
    float e2x = bx-cx, e2y = by-cy, e2z = bz-cz;   // e_jk
    float mnx = fminf(fminf(e0x,e1x),e2x), mny = fminf(fminf(e0y,e1y),e2y), mnz = fminf(fminf(e0z,e1z),e2z);
    float mxx = fmaxf(fmaxf(e0x,e1x),e2x), mxy = fmaxf(fmaxf(e0y,e1y),e2y), mxz = fmaxf(fmaxf(e0z,e1z),e2z);
    float gx = (ax+bx+cx)*(1.0f/3.0f), gy = (ay+by+cy)*(1.0f/3.0f), gz = (az+bz+cz)*(1.0f/3.0f);
    float sq = (gx*gx + gy*gy) + gz*gz;
    if (act) {
        float* g = geo + (size_t)t*12;
        g[0]=mnx; g[1]=mny; g[2]=mnz; g[3]=mxx; g[4]=mxy; g[5]=mxz;
        g[6]=gx;  g[7]=gy;  g[8]=gz;  g[9]=0.f; g[10]=0.f; g[11]=0.f;
        bq[t] = make_float4(gx, gy, gz, sq);
    }
    unsigned n0 = act ? encf(gx) : 0xFFFFFFFFu;
    unsigned n1 = act ? encf(gy) : 0xFFFFFFFFu;
    unsigned n2 = act ? encf(gz) : 0xFFFFFFFFu;
    unsigned x0 = act ? encf(gx) : 0u;
    unsigned x1 = act ? encf(gy) : 0u;
    unsigned x2 = act ? encf(gz) : 0u;
#pragma unroll
    for (int off = 32; off >= 1; off >>= 1) {
        n0 = min(n0, (unsigned)__shfl_xor((int)n0, off));
        n1 = min(n1, (unsigned)__shfl_xor((int)n1, off));
        n2 = min(n2, (unsigned)__shfl_xor((int)n2, off));
        x0 = max(x0, (unsigned)__shfl_xor((int)x0, off));
        x1 = max(x1, (unsigned)__shfl_xor((int)x1, off));
        x2 = max(x2, (unsigned)__shfl_xor((int)x2, off));
    }
    if (lane == 0) {
        atomicMin(&mm[0], n0); atomicMin(&mm[1], n1); atomicMin(&mm[2], n2);
        atomicMax(&mm[3], x0); atomicMax(&mm[4], x1); atomicMax(&mm[5], x2);
    }
}

// ---------------- cell assignment + histogram ----------------
__global__ void cellhist_kernel(const float4* __restrict__ bq, const unsigned* __restrict__ mm,
                                int* __restrict__ cellid, unsigned* __restrict__ hist) {
    int t = blockIdx.x * 256 + threadIdx.x;
    if (t >= T_TRI) return;
    float mnx = decf(mm[0]), mny = decf(mm[1]), mnz = decf(mm[2]);
    float mxx = decf(mm[3]), mxy = decf(mm[4]), mxz = decf(mm[5]);
    float ihx = 16.f / fmaxf(mxx-mnx, 1e-30f);
    float ihy = 16.f / fmaxf(mxy-mny, 1e-30f);
    float ihz = 16.f / fmaxf(mxz-mnz, 1e-30f);
    float4 b = bq[t];
    int ix = min(15, max(0, (int)((b.x-mnx)*ihx)));
    int iy = min(15, max(0, (int)((b.y-mny)*ihy)));
    int iz = min(15, max(0, (int)((b.z-mnz)*ihz)));
    int c = (ix<<8) | (iy<<4) | iz;
    cellid[t] = c;
    atomicAdd(&hist[c], 1u);
}

// ---------------- exclusive prefix over 4096 cells (1 block) ----------------
__global__ __launch_bounds__(1024) void prefix_kernel(const unsigned* __restrict__ hist,
                                                      unsigned* __restrict__ cellstart,
                                                      unsigned* __restrict__ cellptr) {
    __shared__ unsigned sbuf[1024];
    int tid = threadIdx.x;
    uint4 v = ((const uint4*)hist)[tid];
    unsigned mysum = v.x + v.y + v.z + v.w;
    sbuf[tid] = mysum;
    __syncthreads();
    for (int off = 1; off < 1024; off <<= 1) {
        unsigned add = (tid >= off) ? sbuf[tid - off] : 0u;
        __syncthreads();
        sbuf[tid] += add;
        __syncthreads();
    }
    unsigned excl = sbuf[tid] - mysum;
    unsigned p0 = excl, p1 = p0 + v.x, p2 = p1 + v.y, p3 = p2 + v.z;
    cellstart[4*tid+0] = p0; cellstart[4*tid+1] = p1;
    cellstart[4*tid+2] = p2; cellstart[4*tid+3] = p3;
    cellptr[4*tid+0] = p0; cellptr[4*tid+1] = p1;
    cellptr[4*tid+2] = p2; cellptr[4*tid+3] = p3;
    if (tid == 1023) cellstart[4096] = p3 + v.w;
}

// ---------------- scatter into cell-sorted order ----------------
// Intra-cell order is atomic-nondeterministic; the selected top-21 set is
// enumeration-order independent (strict lex order on (d, orig idx)), so the
// OUTPUT is deterministic.
__global__ void scatter_kernel(const float4* __restrict__ bq, const int* __restrict__ cellid,
                               unsigned* __restrict__ cellptr, float4* __restrict__ bqs,
                               int* __restrict__ oid, int* __restrict__ csort) {
    int t = blockIdx.x * 256 + threadIdx.x;
    if (t >= T_TRI) return;
    int c = cellid[t];
    unsigned p = atomicAdd(&cellptr[c], 1u);
    bqs[p] = bq[t];
    oid[p]  = t;
    csort[p] = c;
}

// ---------------- grid KNN: exact top-21, w=1 via z-column ranges ----------------
// R11-verbatim except the w==1 window: cells are lexicographic in (ix,iy,iz),
// so column (ex,ey,z in [Z0,Z1]) is ONE contiguous candidate range -> <=9
// range-drains instead of 27 cell-drains, with the dense CENTER column first
// (tightens theta early; perf heuristic only — candidate set per window is
// identical to R11's cheb<=1 box and selection is order-independent).
// w>=2 rings, stop bound (th < (w*hmin-1e-3)^2; slack dwarfs ~1e-6 formula
// error), distance formula, drain logic, tie-break on ORIGINAL indices: all
// byte-identical to the R11-passing kernel. 1 row/wave — NO union box (R13
// lesson: z/y-wrap in sorted order makes 2-row boxes span the grid).
__global__ __launch_bounds__(256) void knn_grid_kernel(const float4* __restrict__ bqs,
        const int* __restrict__ oid, const int* __restrict__ csort,
        const unsigned* __restrict__ cellstart, const unsigned* __restrict__ mm,
        int* __restrict__ nbr) {
    int wave = threadIdx.x >> 6, lane = threadIdx.x & 63;
    int r = blockIdx.x * 4 + wave;
    float4 q = bqs[r];
    int myc = csort[r];
    int cx = (myc>>8)&15, cy = (myc>>4)&15, cz = myc&15;
    float hx = (decf(mm[3]) - decf(mm[0])) * (1.f/16.f);
    float hy = (decf(mm[4]) - decf(mm[1])) * (1.f/16.f);
    float hz = (decf(mm[5]) - decf(mm[2])) * (1.f/16.f);
    float hmin = fminf(hx, fminf(hy, hz));

    float rd = INFINITY;
    int   ri = 0x7FF00000 | lane;     // distinct sentinels
    float th = INFINITY;
    int   mi = 0x7FFFFFFF;

#define SCAN_RANGE(RS, RE)                                                          \
    for (unsigned base = (RS); base < (RE); base += 64u) {                          \
        unsigned k = base + (unsigned)lane;                                         \
        bool kv = (k < (RE));                                                       \
        float4 c4 = kv ? bqs[k] : make_float4(INFINITY,INFINITY,INFINITY,INFINITY); \
        int ov = kv ? oid[k] : 0x7FFFFFFF;                                          \
        float dot = fmaf(q.z, c4.z, fmaf(q.y, c4.y, q.x*c4.x));                     \
        float d = (q.w + c4.w) - 2.0f*dot;                                          \
        unsigned long long bal = __ballot(kv && (d <= th));                         \
        while (bal) {                                                               \
            int src = __ffsll(bal) - 1; bal &= bal - 1;                             \
            float dc = readlane_f(d, src);                                          \
            int   jc = __builtin_amdgcn_readlane(ov, src);                          \
            if ((dc < th) || (dc == th && jc < mi)) {                               \
                bool less = (rd < dc) || (rd == dc && ri < jc);                     \
                int pos = __popcll(__ballot(less) & 0x1FFFFFull);                   \
                float sd = __shfl_up(rd, 1);                                        \
                int   si = __shfl_up(ri, 1);                                        \
                if (lane < 21) {                                                    \
                    if (lane == pos)      { rd = dc; ri = jc; }                     \
                    else if (lane > pos)  { rd = sd; ri = si; }                     \
                }                                                                   \
                th = readlane_f(rd, 20);                                            \
                mi = __builtin_amdgcn_readlane(ri, 20);                             \
            }                                                                       \
        }                                                                           \
    }

    for (int w = 1; w <= 15; ++w) {
        if (w == 1) {
            int X0 = max(cx-1, 0), X1 = min(cx+1, 15);
            int Y0 = max(cy-1, 0), Y1 = min(cy+1, 15);
            int Z0 = max(cz-1, 0), Z1 = min(cz+1, 15);
            int Wy = Y1 - Y0 + 1;
            int ncol = (X1 - X0 + 1) * Wy;      // <= 9
            int i = lane;
            bool val = (i < ncol);
            int ii = val ? i : 0;
            int ex = X0 + ii / Wy, ey = Y0 + ii % Wy;
            int colb = (ex<<8) | (ey<<4);
            unsigned cs = 0u, ce = 0u;
            if (val) { cs = cellstart[colb + Z0]; ce = cellstart[colb + Z1 + 1]; }
            val = val && (cs < ce);
            unsigned long long cm = __ballot(val);
            int j0 = (cx - X0)*Wy + (cy - Y0);   // center column (always < ncol)
            if ((cm >> j0) & 1ull) {
                unsigned s0 = (unsigned)__builtin_amdgcn_readlane((int)cs, j0);
                unsigned e0 = (unsigned)__builtin_amdgcn_readlane((int)ce, j0);
                SCAN_RANGE(s0, e0)
                cm &= ~(1ull << j0);
            }
            while (cm) {
                int cl = __ffsll(cm) - 1; cm &= cm - 1;
                unsigned s0 = (unsigned)__builtin_amdgcn_readlane((int)cs, cl);
                unsigned e0 = (unsigned)__builtin_amdgcn_readlane((int)ce, cl);
                SCAN_RANGE(s0, e0)
            }
        } else {
            int W = 2*w + 1, W2 = W*W, tot = W*W2;
            for (int b0 = 0; b0 < tot; b0 += 64) {
                int i = b0 + lane;
                bool val = (i < tot);
                int ii = val ? i : 0;
                int dz = ii % W - w, dy = (ii / W) % W - w, dx = ii / W2 - w;
                int cheb = max(abs(dx), max(abs(dy), abs(dz)));
                val = val && (cheb == w);
                int ex = cx + dx, ey = cy + dy, ez = cz + dz;
                val = val && ex >= 0 && ex < 16 && ey >= 0 && ey < 16 && ez >= 0 && ez < 16;
                int cell = (ex<<8) | (ey<<4) | ez;
                unsigned cs = 0u, ce = 0u;
                if (val) { cs = cellstart[cell]; ce = cellstart[cell+1]; }
                val = val && (cs < ce);
                unsigned long long cm = __ballot(val);
                while (cm) {
                    int cl = __ffsll(cm) - 1; cm &= cm - 1;
                    unsigned s0 = (unsigned)__builtin_amdgcn_readlane((int)cs, cl);
                    unsigned e0 = (unsigned)__builtin_amdgcn_readlane((int)ce, cl);
                    SCAN_RANGE(s0, e0)
                }
            }
        }
        bool covered = (cx-w <= 0) && (cx+w >= 15) && (cy-w <= 0) && (cy+w >= 15)
                    && (cz-w <= 0) && (cz+w >= 15);
        if (covered) break;
        float bd = (float)w * hmin - 1e-3f;
        if (bd > 0.f && th < bd*bd) break;
    }
#undef SCAN_RANGE
    // lane l holds rank-l entry (orig indices); rank 0 = self, dropped
    if (lane >= 1 && lane < 21) nbr[oid[r]*KNN_K + lane - 1] = ri;
}

// ---------------- layer-0 helpers: y0[t][f] = p[t] * rowsum(W1b)[f] ----------------
__global__ void rowsum_kernel(const float* __restrict__ W1, float* __restrict__ rs) {
    int f = threadIdx.x;
    float s = 0.f;
    for (int c = 0; c < H; ++c) s += W1[f*137 + 9 + c];
    rs[f] = s;
}
__global__ void y0_kernel(const float* __restrict__ p, const float* __restrict__ rs, float* __restrict__ Y) {
    int tid = blockIdx.x * blockDim.x + threadIdx.x;   // over T*H
    int t = tid >> 7, f = tid & 127;
    Y[tid] = p[t] * rs[f];
}

// ---------------- weight pre-transpose (once, tiny) ----------------
__global__ void wtrans_kernel(const float* __restrict__ W11, const float* __restrict__ W12,
                              const float* __restrict__ W20, const float* __restrict__ W21,
                              const float* __restrict__ W22, float* __restrict__ WTg) {
    int f = threadIdx.x, c = blockIdx.x, m = blockIdx.y;
    const float* W; int stride, col0;
    if      (m == 0) { W = W11; stride = 137; col0 = 9; }
    else if (m == 1) { W = W12; stride = 137; col0 = 9; }
    else if (m == 2) { W = W20; stride = 128; col0 = 0; }
    else if (m == 3) { W = W21; stride = 128; col0 = 0; }
    else             { W = W22; stride = 128; col0 = 0; }
    WTg[m*16384 + (c>>2)*512 + f*4 + (c&3)] = W[f*stride + col0 + c];
}

// ---------------- standalone dense (the W1b mid-layer GEMM): Y = X@W1b^T ----------------
#define DTPB 16
__global__ __launch_bounds__(128) void dense_kernel(const float* __restrict__ A, const float* __restrict__ WTg,
                             float* __restrict__ C) {
    __shared__ float Ar[8][128];
    int f = threadIdx.x;
    int t0 = blockIdx.x * DTPB;
    for (int tt = 0; tt < DTPB; tt += 8) {
        __syncthreads();
#pragma unroll
        for (int j = 0; j < 8; ++j) Ar[j][f] = A[(size_t)(t0+tt+j)*H + f];
        __syncthreads();
        float a0 = 0.f, a1 = 0.f, a2 = 0.f, a3 = 0.f;
        float a4_ = 0.f, a5 = 0.f, a6 = 0.f, a7 = 0.f;
#pragma unroll
        for (int c4 = 0; c4 < 32; ++c4) {
            float4 w = *(const float4*)&WTg[c4*512 + f*4];
#define DROW(J, ACC)                                                        \
            {                                                               \
                float4 v = ((const float4*)Ar[J])[c4];                      \
                ACC = fmaf(w.x, v.x, ACC); ACC = fmaf(w.y, v.y, ACC);       \
                ACC = fmaf(w.z, v.z, ACC); ACC = fmaf(w.w, v.w, ACC);       \
            }
            DROW(0, a0) DROW(1, a1) DROW(2, a2) DROW(3, a3)
            DROW(4, a4_) DROW(5, a5) DROW(6, a6) DROW(7, a7)
#undef DROW
        }
        C[(size_t)(t0+tt+0)*H + f] = a0;
        C[(size_t)(t0+tt+1)*H + f] = a1;
        C[(size_t)(t0+tt+2)*H + f] = a2;
        C[(size_t)(t0+tt+3)*H + f] = a3;
        C[(size_t)(t0+tt+4)*H + f] = a4_;
        C[(size_t)(t0+tt+5)*H + f] = a5;
        C[(size_t)(t0+tt+6)*H + f] = a6;
        C[(size_t)(t0+tt+7)*H + f] = a7;
    }
}

// ---------------- fused edge + W2 (+ head) — R10/R11-passing version ----------------
__global__ __launch_bounds__(256) void edgefused_kernel(const float* __restrict__ Y, const float* __restrict__ geo,
                            const int* __restrict__ nbr, const float* __restrict__ W1,
                            const float* __restrict__ b1, const float* __restrict__ WTg,
                            const float* __restrict__ b2, float* __restrict__ X,
                            const float* __restrict__ Wf, const float* __restrict__ bf,
                            float* __restrict__ out, int last) {
    __shared__ float W1aT[9][128];
    __shared__ float Srow[4][128];
    __shared__ float fpart[4][2];
    for (int idx = threadIdx.x; idx < 9*128; idx += 256) {
        int c = idx >> 7, ff = idx & 127;
        W1aT[c][ff] = W1[ff*137 + c];
    }
    __syncthreads();
    int wave = threadIdx.x >> 6, lane = threadIdx.x & 63;
    int t0b = blockIdx.x * 4;
    {
        int t = t0b + wave;
        float wlo[9], whi[9];
#pragma unroll
        for (int c = 0; c < 9; ++c) { wlo[c] = W1aT[c][lane]; whi[c] = W1aT[c][64+lane]; }
        const float4* g4 = (const float4*)geo;
        float4 s0 = g4[t*3+0], s1 = g4[t*3+1], s2 = g4[t*3+2];
        float b1lo = b1[lane],            b1hi = b1[64+lane];
        float ylo  = Y[(size_t)t*H+lane], yhi  = Y[(size_t)t*H+64+lane];
        float accLo = 0.f, accHi = 0.f;
#pragma unroll
        for (int e = 0; e < KNN_K; ++e) {
            int tg = nbr[t*KNN_K + e];
            float4 t0 = g4[tg*3+0], t1 = g4[tg*3+1], t2 = g4[tg*3+2];
            float r0 = s0.x-t0.x, r1 = s0.y-t0.y, r2 = s0.z-t0.z, r3 = s0.w-t0.w;
            float r4 = s1.x-t1.x, r5 = s1.y-t1.y, r6 = s1.z-t1.z, r7 = s1.w-t1.w;
            float r8 = s2.x-t2.x;
            float gLo = b1lo;
            gLo = fmaf(wlo[0], r0, gLo); gLo = fmaf(wlo[1], r1, gLo); gLo = fmaf(wlo[2], r2, gLo);
            gLo = fmaf(wlo[3], r3, gLo); gLo = fmaf(wlo[4], r4, gLo);
            gLo = fmaf(wlo[5], r5, gLo); gLo = fmaf(wlo[6], r6, gLo);
            gLo = fmaf(wlo[7], r7, gLo); gLo = fmaf(wlo[8], r8, gLo);
            float gHi = b1hi;
            gHi = fmaf(whi[0], r0, gHi); gHi = fmaf(whi[1], r1, gHi); gHi = fmaf(whi[2], r2, gHi);
            gHi = fmaf(whi[3], r3, gHi); gHi = fmaf(whi[4], r4, gHi);
            gHi = fmaf(whi[5], r5, gHi); gHi = fmaf(whi[6], r6, gHi);
            gHi = fmaf(whi[7], r7, gHi); gHi = fmaf(whi[8], r8, gHi);
            accLo += fmaxf(gLo + ylo - Y[(size_t)tg*H + lane], 0.f);
            accHi += fmaxf(gHi + yhi - Y[(size_t)tg*H + 64 + lane], 0.f);
        }
        Srow[wave][lane]    = accLo;
        Srow[wave][64+lane] = accHi;
    }
    __syncthreads();
    int f = threadIdx.x & 127, half = threadIdx.x >> 7;
    float base = b2[f] * (float)KNN_K;
    float a0 = base, a1 = base;
    const int r0_ = half * 2;
#pragma unroll
    for (int c4 = 0; c4 < 32; ++c4) {
        float4 w = *(const float4*)&WTg[c4*512 + f*4];
        float4 v0 = ((const float4*)Srow[r0_+0])[c4];
        float4 v1 = ((const float4*)Srow[r0_+1])[c4];
        a0 = fmaf(w.x, v0.x, a0); a0 = fmaf(w.y, v0.y, a0);
        a0 = fmaf(w.z, v0.z, a0); a0 = fmaf(w.w, v0.w, a0);
        a1 = fmaf(w.x, v1.x, a1); a1 = fmaf(w.y, v1.y, a1);
        a1 = fmaf(w.z, v1.z, a1); a1 = fmaf(w.w, v1.w, a1);
    }
    if (!last) {
        X[(size_t)(t0b+r0_+0)*H + f] = a0;
        X[(size_t)(t0b+r0_+1)*H + f] = a1;
    } else {
        float wf = Wf[f];
        float p0 = a0*wf, p1 = a1*wf;
#pragma unroll
        for (int off = 32; off >= 1; off >>= 1) {
            p0 += __shfl_xor(p0, off);
            p1 += __shfl_xor(p1, off);
        }
        if (lane == 0) { fpart[wave][0] = p0; fpart[wave][1] = p1; }
        __syncthreads();
        if (threadIdx.x < 4) {
            int rr = threadIdx.x;
            int h = rr >> 1, j = rr & 1;
            float z = fpart[2*h][j] + fpart[2*h+1][j] + bf[0];
            out[t0b + h*2 + j] = 1.0f / (1.0f + expf(-z));
        }
    }
}

extern "C" void kernel_launch(void* const* d_in, const int* in_sizes, int n_in,
                              void* d_out, int out_size, void* d_ws, size_t ws_size,
                              hipStream_t stream) {
    (void)in_sizes; (void)n_in; (void)out_size; (void)ws_size;
    const float* pts   = (const float*)d_in[0];
    const int*   tris  = (const int*)d_in[1];
    const float* probs = (const float*)d_in[2];
    const float* W1[3] = {(const float*)d_in[3],  (const float*)d_in[7],  (const float*)d_in[11]};
    const float* b1[3] = {(const float*)d_in[4],  (const float*)d_in[8],  (const float*)d_in[12]};
    const float* W2[3] = {(const float*)d_in[5],  (const float*)d_in[9],  (const float*)d_in[13]};
    const float* b2[3] = {(const float*)d_in[6],  (const float*)d_in[10], (const float*)d_in[14]};
    const float* Wf = (const float*)d_in[15];
    const float* bf = (const float*)d_in[16];
    float* out = (float*)d_out;

    char* ws = (char*)d_ws;
    float*    geo  = (float*)(ws + WS_GEO);
    float4*   bq   = (float4*)(ws + WS_BQ);
    int*      nbr  = (int*)(ws + WS_NBR);
    float*    rs   = (float*)(ws + WS_RS);
    float*    WTg  = (float*)(ws + WS_WT);
    unsigned* mm   = (unsigned*)(ws + WS_MM);
    unsigned* cst  = (unsigned*)(ws + WS_CSTART);
    unsigned* cptr = (unsigned*)(ws + WS_CPTR);
    unsigned* hist = (unsigned*)(ws + WS_HIST);
    int*      cid  = (int*)(ws + WS_CID);
    int*      cso  = (int*)(ws + WS_CSORT);
    int*      oid  = (int*)(ws + WS_OID);
    float4*   bqs  = (float4*)(ws + WS_BQS);
    float*    X    = (float*)(ws + WS_X);
    float*    Y    = (float*)(ws + WS_Y);

    grid_init_kernel<<<16, 256, 0, stream>>>(hist, mm);
    geom_kernel<<<(T_TRI+255)/256, 256, 0, stream>>>(pts, tris, geo, bq, mm);
    cellhist_kernel<<<(T_TRI+255)/256, 256, 0, stream>>>(bq, mm, cid, hist);
    prefix_kernel<<<1, 1024, 0, stream>>>(hist, cst, cptr);
    scatter_kernel<<<(T_TRI+255)/256, 256, 0, stream>>>(bq, cid, cptr, bqs, oid, cso);
    knn_grid_kernel<<<T_TRI/4, 256, 0, stream>>>(bqs, oid, cso, cst, mm, nbr);
    rowsum_kernel<<<1, 128, 0, stream>>>(W1[0], rs);
    wtrans_kernel<<<dim3(128,5), 128, 0, stream>>>(W1[1], W1[2], W2[0], W2[1], W2[2], WTg);
    y0_kernel<<<(T_TRI*H)/256, 256, 0, stream>>>(probs, rs, Y);
    for (int l = 0; l < 3; ++l) {
        if (l > 0)
            dense_kernel<<<T_TRI/DTPB, 128, 0, stream>>>(X, WTg + (size_t)(l-1)*16384, Y);
        edgefused_kernel<<<T_TRI/4, 256, 0, stream>>>(Y, geo, nbr, W1[l], b1[l],
                                                      WTg + (size_t)(2+l)*16384, b2[l], X,
                                                      Wf, bf, out, (l == 2) ? 1 : 0);
    }
}

// Round 15
// 466.452 us; speedup vs baseline: 1.6578x; 1.0174x over previous
//
#include <hip/hip_runtime.h>
#include <math.h>

#define T_TRI 20000
#define KNN_K 20
#define H     128

// ---------------- workspace layout (bytes) ----------------
#define WS_GEO    0                       // 960KB (original-space geo)
#define WS_BQ     (1u<<20)                // 320KB
#define WS_NBR    (2u<<20)                // 1.6MB (sorted-space neighbor lists)
#define WS_RS     (4u<<20)                // 512B
#define WS_WT     ((4u<<20)+4096)         // 320KB
#define WS_MM     (5u<<20)                // 64B
#define WS_CSTART ((5u<<20)+64)           // 4097 u32
#define WS_CPTR   ((5u<<20)+(32u<<10))    // 4096 u32
#define WS_HIST   ((5u<<20)+(64u<<10))    // 4096 u32
#define WS_CID    ((5u<<20)+(128u<<10))   // 20000 i32
#define WS_CSORT  ((5u<<20)+(256u<<10))   // 20000 i32
#define WS_OID    ((5u<<20)+(384u<<10))   // 20000 i32
#define WS_BQS    ((5u<<20)+(512u<<10))   // 20000 float4
#define WS_PS     (6u<<20)                // 80KB (probs_s)
#define WS_GEOS   (7u<<20)                // 960KB (sorted-space geo)
#define WS_X      (9u<<20)
#define WS_Y      (20u<<20)

__device__ __forceinline__ float readlane_f(float v, int l) {
    return __uint_as_float(__builtin_amdgcn_readlane(__float_as_uint(v), l));
}
// order-preserving float<->uint (for atomicMin/Max on floats)
__device__ __forceinline__ unsigned encf(float f) {
    unsigned u = __float_as_uint(f);
    return (u & 0x80000000u) ? ~u : (u | 0x80000000u);
}
__device__ __forceinline__ float decf(unsigned e) {
    unsigned u = (e & 0x80000000u) ? (e & 0x7FFFFFFFu) : ~e;
    return __uint_as_float(u);
}
// m204 bijective XCD swizzle: HW places block B on XCD B%8; give it logical
// work from chunk (B%8) so contiguous row-chunks live on one XCD's L2.
// Producer (y0/dense) and consumer (edgefused) use the same mapping -> a
// row's Y/X data is written and read on the SAME XCD. Bijective for any nwg.
__device__ __forceinline__ int xcd_swz(int bid, int nwg) {
    int q = nwg >> 3, rm = nwg & 7;
    int x = bid & 7, idx = bid >> 3;
    return (x < rm) ? x*(q+1) + idx : rm*(q+1) + (x-rm)*q + idx;
}

// ---------------- init: zero histogram, minmax sentinels ----------------
__global__ void grid_init_kernel(unsigned* __restrict__ hist, unsigned* __restrict__ mm) {
    int i = blockIdx.x * 256 + threadIdx.x;
    if (i < 4096) hist[i] = 0u;
    if (i < 3) mm[i] = 0xFFFFFFFFu;          // mins (uint-encoded)
    if (i >= 3 && i < 6) mm[i] = 0u;         // maxs
}

// ---------------- geometry (+ bary AABB via wave-reduced atomics) ----------------
__global__ void geom_kernel(const float* __restrict__ pts, const int* __restrict__ tris,
                            float* __restrict__ geo, float4* __restrict__ bq,
                            unsigned* __restrict__ mm) {
    int t = blockIdx.x * blockDim.x + threadIdx.x;
    int lane = threadIdx.x & 63;
    bool act = (t < T_TRI);
    int tt = act ? t : 0;
    int i0 = tris[3*tt], i1 = tris[3*tt+1], i2 = tris[3*tt+2];
    float ax = pts[3*i0], ay = pts[3*i0+1], az = pts[3*i0+2];
    float bx = pts[3*i1], by = pts[3*i1+1], bz = pts[3*i1+2];
    float cx = pts[3*i2], cy = pts[3*i2+1], cz = pts[3*i2+2];
    float e0x = ax-bx, e0y = ay-by, e0z = az-bz;   // e_ij
    float e1x = ax-cx, e1y = ay-cy, e1z = az-cz;   // e_ik
    float e2x = bx-cx, e2y = by-cy, e2z = bz-cz;   // e_jk
    float mnx = fminf(fminf(e0x,e1x),e2x), mny = fminf(fminf(e0y,e1y),e2y), mnz = fminf(fminf(e0z,e1z),e2z);
    float mxx = fmaxf(fmaxf(e0x,e1x),e2x), mxy = fmaxf(fmaxf(e0y,e1y),e2y), mxz = fmaxf(fmaxf(e0z,e1z),e2z);
    float gx = (ax+bx+cx)*(1.0f/3.0f), gy = (ay+by+cy)*(1.0f/3.0f), gz = (az+bz+cz)*(1.0f/3.0f);
    float sq = (gx*gx + gy*gy) + gz*gz;
    if (act) {
        float* g = geo + (size_t)t*12;
        g[0]=mnx; g[1]=mny; g[2]=mnz; g[3]=mxx; g[4]=mxy; g[5]=mxz;
        g[6]=gx;  g[7]=gy;  g[8]=gz;  g[9]=0.f; g[10]=0.f; g[11]=0.f;
        bq[t] = make_float4(gx, gy, gz, sq);
    }
    unsigned n0 = act ? encf(gx) : 0xFFFFFFFFu;
    unsigned n1 = act ? encf(gy) : 0xFFFFFFFFu;
    unsigned n2 = act ? encf(gz) : 0xFFFFFFFFu;
    unsigned x0 = act ? encf(gx) : 0u;
    unsigned x1 = act ? encf(gy) : 0u;
    unsigned x2 = act ? encf(gz) : 0u;
#pragma unroll
    for (int off = 32; off >= 1; off >>= 1) {
        n0 = min(n0, (unsigned)__shfl_xor((int)n0, off));
        n1 = min(n1, (unsigned)__shfl_xor((int)n1, off));
        n2 = min(n2, (unsigned)__shfl_xor((int)n2, off));
        x0 = max(x0, (unsigned)__shfl_xor((int)x0, off));
        x1 = max(x1, (unsigned)__shfl_xor((int)x1, off));
        x2 = max(x2, (unsigned)__shfl_xor((int)x2, off));
    }
    if (lane == 0) {
        atomicMin(&mm[0], n0); atomicMin(&mm[1], n1); atomicMin(&mm[2], n2);
        atomicMax(&mm[3], x0); atomicMax(&mm[4], x1); atomicMax(&mm[5], x2);
    }
}

// ---------------- cell assignment + histogram ----------------
__global__ void cellhist_kernel(const float4* __restrict__ bq, const unsigned* __restrict__ mm,
                                int* __restrict__ cellid, unsigned* __restrict__ hist) {
    int t = blockIdx.x * 256 + threadIdx.x;
    if (t >= T_TRI) return;
    float mnx = decf(mm[0]), mny = decf(mm[1]), mnz = decf(mm[2]);
    float mxx = decf(mm[3]), mxy = decf(mm[4]), mxz = decf(mm[5]);
    float ihx = 16.f / fmaxf(mxx-mnx, 1e-30f);
    float ihy = 16.f / fmaxf(mxy-mny, 1e-30f);
    float ihz = 16.f / fmaxf(mxz-mnz, 1e-30f);
    float4 b = bq[t];
    int ix = min(15, max(0, (int)((b.x-mnx)*ihx)));
    int iy = min(15, max(0, (int)((b.y-mny)*ihy)));
    int iz = min(15, max(0, (int)((b.z-mnz)*ihz)));
    int c = (ix<<8) | (iy<<4) | iz;
    cellid[t] = c;
    atomicAdd(&hist[c], 1u);
}

// ---------------- exclusive prefix over 4096 cells (1 block) ----------------
__global__ __launch_bounds__(1024) void prefix_kernel(const unsigned* __restrict__ hist,
                                                      unsigned* __restrict__ cellstart,
                                                      unsigned* __restrict__ cellptr) {
    __shared__ unsigned sbuf[1024];
    int tid = threadIdx.x;
    uint4 v = ((const uint4*)hist)[tid];
    unsigned mysum = v.x + v.y + v.z + v.w;
    sbuf[tid] = mysum;
    __syncthreads();
    for (int off = 1; off < 1024; off <<= 1) {
        unsigned add = (tid >= off) ? sbuf[tid - off] : 0u;
        __syncthreads();
        sbuf[tid] += add;
        __syncthreads();
    }
    unsigned excl = sbuf[tid] - mysum;
    unsigned p0 = excl, p1 = p0 + v.x, p2 = p1 + v.y, p3 = p2 + v.z;
    cellstart[4*tid+0] = p0; cellstart[4*tid+1] = p1;
    cellstart[4*tid+2] = p2; cellstart[4*tid+3] = p3;
    cellptr[4*tid+0] = p0; cellptr[4*tid+1] = p1;
    cellptr[4*tid+2] = p2; cellptr[4*tid+3] = p3;
    if (tid == 1023) cellstart[4096] = p3 + v.w;
}

// ---------------- scatter into cell-sorted order (+ relabeled geo/probs) ----------------
// Intra-cell order is atomic-nondeterministic; the selected top-21 set is
// enumeration-order independent (strict lex order on (d, orig idx)), so the
// OUTPUT is deterministic. geo_s/probs_s let the layer pipeline run in sorted
// (spatially-local) index space — R12-passed structure.
__global__ void scatter_kernel(const float4* __restrict__ bq, const int* __restrict__ cellid,
                               const float* __restrict__ geo, const float* __restrict__ probs,
                               unsigned* __restrict__ cellptr, float4* __restrict__ bqs,
                               int* __restrict__ oid, int* __restrict__ csort,
                               float* __restrict__ geo_s, float* __restrict__ probs_s) {
    int t = blockIdx.x * 256 + threadIdx.x;
    if (t >= T_TRI) return;
    int c = cellid[t];
    unsigned p = atomicAdd(&cellptr[c], 1u);
    bqs[p] = bq[t];
    oid[p]  = t;
    csort[p] = c;
    const float4* g4 = (const float4*)geo;
    float4* g4s = (float4*)geo_s;
    g4s[(size_t)p*3+0] = g4[(size_t)t*3+0];
    g4s[(size_t)p*3+1] = g4[(size_t)t*3+1];
    g4s[(size_t)p*3+2] = g4[(size_t)t*3+2];
    probs_s[p] = probs[t];
}

// ---------------- grid KNN: R14-passing kernel + sorted-index payload ----------------
// w=1 via z-column ranges (center column first), w>=2 rings, stop bound
// th < (w*hmin-1e-3)^2, distance formula, drain logic, tie-break on ORIGINAL
// indices: all byte-identical to R14. Only addition (R12-proven): the insert
// network also carries the SORTED index rk so nbr is emitted in sorted space.
__global__ __launch_bounds__(256) void knn_grid_kernel(const float4* __restrict__ bqs,
        const int* __restrict__ oid, const int* __restrict__ csort,
        const unsigned* __restrict__ cellstart, const unsigned* __restrict__ mm,
        int* __restrict__ nbr) {
    int wave = threadIdx.x >> 6, lane = threadIdx.x & 63;
    int r = blockIdx.x * 4 + wave;
    float4 q = bqs[r];
    int myc = csort[r];
    int cx = (myc>>8)&15, cy = (myc>>4)&15, cz = myc&15;
    float hx = (decf(mm[3]) - decf(mm[0])) * (1.f/16.f);
    float hy = (decf(mm[4]) - decf(mm[1])) * (1.f/16.f);
    float hz = (decf(mm[5]) - decf(mm[2])) * (1.f/16.f);
    float hmin = fminf(hx, fminf(hy, hz));

    float rd = INFINITY;
    int   ri = 0x7FF00000 | lane;     // distinct sentinels (orig-idx key)
    int   rk = lane;                  // sorted-idx payload
    float th = INFINITY;
    int   mi = 0x7FFFFFFF;

#define SCAN_RANGE(RS, RE)                                                          \
    for (unsigned base = (RS); base < (RE); base += 64u) {                          \
        unsigned k = base + (unsigned)lane;                                         \
        bool kv = (k < (RE));                                                       \
        float4 c4 = kv ? bqs[k] : make_float4(INFINITY,INFINITY,INFINITY,INFINITY); \
        int ov = kv ? oid[k] : 0x7FFFFFFF;                                          \
        float dot = fmaf(q.z, c4.z, fmaf(q.y, c4.y, q.x*c4.x));                     \
        float d = (q.w + c4.w) - 2.0f*dot;                                          \
        unsigned long long bal = __ballot(kv && (d <= th));                         \
        while (bal) {                                                               \
            int src = __ffsll(bal) - 1; bal &= bal - 1;                             \
            float dc = readlane_f(d, src);                                          \
            int   jc = __builtin_amdgcn_readlane(ov, src);                          \
            int   kc = (int)base + src;                                             \
            if ((dc < th) || (dc == th && jc < mi)) {                               \
                bool less = (rd < dc) || (rd == dc && ri < jc);                     \
                int pos = __popcll(__ballot(less) & 0x1FFFFFull);                   \
                float sd = __shfl_up(rd, 1);                                        \
                int   si = __shfl_up(ri, 1);                                        \
                int   sk = __shfl_up(rk, 1);                                        \
                if (lane < 21) {                                                    \
                    if (lane == pos)      { rd = dc; ri = jc; rk = kc; }            \
                    else if (lane > pos)  { rd = sd; ri = si; rk = sk; }            \
                }                                                                   \
                th = readlane_f(rd, 20);                                            \
                mi = __builtin_amdgcn_readlane(ri, 20);                             \
            }                                                                       \
        }                                                                           \
    }

    for (int w = 1; w <= 15; ++w) {
        if (w == 1) {
            int X0 = max(cx-1, 0), X1 = min(cx+1, 15);
            int Y0 = max(cy-1, 0), Y1 = min(cy+1, 15);
            int Z0 = max(cz-1, 0), Z1 = min(cz+1, 15);
            int Wy = Y1 - Y0 + 1;
            int ncol = (X1 - X0 + 1) * Wy;      // <= 9
            int i = lane;
            bool val = (i < ncol);
            int ii = val ? i : 0;
            int ex = X0 + ii / Wy, ey = Y0 + ii % Wy;
            int colb = (ex<<8) | (ey<<4);
            unsigned cs = 0u, ce = 0u;
            if (val) { cs = cellstart[colb + Z0]; ce = cellstart[colb + Z1 + 1]; }
            val = val && (cs < ce);
            unsigned long long cm = __ballot(val);
            int j0 = (cx - X0)*Wy + (cy - Y0);   // center column (always < ncol)
            if ((cm >> j0) & 1ull) {
                unsigned s0 = (unsigned)__builtin_amdgcn_readlane((int)cs, j0);
                unsigned e0 = (unsigned)__builtin_amdgcn_readlane((int)ce, j0);
                SCAN_RANGE(s0, e0)
                cm &= ~(1ull << j0);
            }
            while (cm) {
                int cl = __ffsll(cm) - 1; cm &= cm - 1;
                unsigned s0 = (unsigned)__builtin_amdgcn_readlane((int)cs, cl);
                unsigned e0 = (unsigned)__builtin_amdgcn_readlane((int)ce, cl);
                SCAN_RANGE(s0, e0)
            }
        } else {
            int W = 2*w + 1, W2 = W*W, tot = W*W2;
            for (int b0 = 0; b0 < tot; b0 += 64) {
                int i = b0 + lane;
                bool val = (i < tot);
                int ii = val ? i : 0;
                int dz = ii % W - w, dy = (ii / W) % W - w, dx = ii / W2 - w;
                int cheb = max(abs(dx), max(abs(dy), abs(dz)));
                val = val && (cheb == w);
                int ex = cx + dx, ey = cy + dy, ez = cz + dz;
                val = val && ex >= 0 && ex < 16 && ey >= 0 && ey < 16 && ez >= 0 && ez < 16;
                int cell = (ex<<8) | (ey<<4) | ez;
                unsigned cs = 0u, ce = 0u;
                if (val) { cs = cellstart[cell]; ce = cellstart[cell+1]; }
                val = val && (cs < ce);
                unsigned long long cm = __ballot(val);
                while (cm) {
                    int cl = __ffsll(cm) - 1; cm &= cm - 1;
                    unsigned s0 = (unsigned)__builtin_amdgcn_readlane((int)cs, cl);
                    unsigned e0 = (unsigned)__builtin_amdgcn_readlane((int)ce, cl);
                    SCAN_RANGE(s0, e0)
                }
            }
        }
        bool covered = (cx-w <= 0) && (cx+w >= 15) && (cy-w <= 0) && (cy+w >= 15)
                    && (cz-w <= 0) && (cz+w >= 15);
        if (covered) break;
        float bd = (float)w * hmin - 1e-3f;
        if (bd > 0.f && th < bd*bd) break;
    }
#undef SCAN_RANGE
    // lane l holds rank-l entry; rank 0 = self, dropped; emit SORTED index
    if (lane >= 1 && lane < 21) nbr[r*KNN_K + lane - 1] = rk;
}

// ---------------- layer-0 helpers (sorted space, XCD-swizzled) ----------------
__global__ void rowsum_kernel(const float* __restrict__ W1, float* __restrict__ rs) {
    int f = threadIdx.x;
    float s = 0.f;
    for (int c = 0; c < H; ++c) s += W1[f*137 + 9 + c];
    rs[f] = s;
}
__global__ void y0_kernel(const float* __restrict__ ps, const float* __restrict__ rs, float* __restrict__ Y) {
    int bid = xcd_swz(blockIdx.x, gridDim.x);
    int tid = bid * 256 + threadIdx.x;   // over T*H
    int t = tid >> 7, f = tid & 127;
    Y[tid] = ps[t] * rs[f];
}

// ---------------- weight pre-transpose (once, tiny) ----------------
__global__ void wtrans_kernel(const float* __restrict__ W11, const float* __restrict__ W12,
                              const float* __restrict__ W20, const float* __restrict__ W21,
                              const float* __restrict__ W22, float* __restrict__ WTg) {
    int f = threadIdx.x, c = blockIdx.x, m = blockIdx.y;
    const float* W; int stride, col0;
    if      (m == 0) { W = W11; stride = 137; col0 = 9; }
    else if (m == 1) { W = W12; stride = 137; col0 = 9; }
    else if (m == 2) { W = W20; stride = 128; col0 = 0; }
    else if (m == 3) { W = W21; stride = 128; col0 = 0; }
    else             { W = W22; stride = 128; col0 = 0; }
    WTg[m*16384 + (c>>2)*512 + f*4 + (c&3)] = W[f*stride + col0 + c];
}

// ---------------- standalone dense (sorted space, XCD-swizzled): Y = X@W1b^T ----------------
#define DTPB 16
__global__ __launch_bounds__(128) void dense_kernel(const float* __restrict__ A, const float* __restrict__ WTg,
                             float* __restrict__ C) {
    __shared__ float Ar[8][128];
    int f = threadIdx.x;
    int t0 = xcd_swz(blockIdx.x, gridDim.x) * DTPB;
    for (int tt = 0; tt < DTPB; tt += 8) {
        __syncthreads();
#pragma unroll
        for (int j = 0; j < 8; ++j) Ar[j][f] = A[(size_t)(t0+tt+j)*H + f];
        __syncthreads();
        float a0 = 0.f, a1 = 0.f, a2 = 0.f, a3 = 0.f;
        float a4_ = 0.f, a5 = 0.f, a6 = 0.f, a7 = 0.f;
#pragma unroll
        for (int c4 = 0; c4 < 32; ++c4) {
            float4 w = *(const float4*)&WTg[c4*512 + f*4];
#define DROW(J, ACC)                                                        \
            {                                                               \
                float4 v = ((const float4*)Ar[J])[c4];                      \
                ACC = fmaf(w.x, v.x, ACC); ACC = fmaf(w.y, v.y, ACC);       \
                ACC = fmaf(w.z, v.z, ACC); ACC = fmaf(w.w, v.w, ACC);       \
            }
            DROW(0, a0) DROW(1, a1) DROW(2, a2) DROW(3, a3)
            DROW(4, a4_) DROW(5, a5) DROW(6, a6) DROW(7, a7)
#undef DROW
        }
        C[(size_t)(t0+tt+0)*H + f] = a0;
        C[(size_t)(t0+tt+1)*H + f] = a1;
        C[(size_t)(t0+tt+2)*H + f] = a2;
        C[(size_t)(t0+tt+3)*H + f] = a3;
        C[(size_t)(t0+tt+4)*H + f] = a4_;
        C[(size_t)(t0+tt+5)*H + f] = a5;
        C[(size_t)(t0+tt+6)*H + f] = a6;
        C[(size_t)(t0+tt+7)*H + f] = a7;
    }
}

// ---------------- fused edge + W2 (+ head), sorted space, XCD-swizzled ----------------
// R12-passed structure; the swizzle aligns this kernel's row-chunks with the
// producer kernels' chunks so neighbor Y/geo gathers hit the local XCD L2.
__global__ __launch_bounds__(256) void edgefused_kernel(const float* __restrict__ Y, const float* __restrict__ geo_s,
                            const int* __restrict__ nbr, const float* __restrict__ W1,
                            const float* __restrict__ b1, const float* __restrict__ WTg,
                            const float* __restrict__ b2, float* __restrict__ X,
                            const float* __restrict__ Wf, const float* __restrict__ bf,
                            float* __restrict__ out, const int* __restrict__ oid, int last) {
    __shared__ float W1aT[9][128];
    __shared__ float Srow[4][128];
    __shared__ float fpart[4][2];
    for (int idx = threadIdx.x; idx < 9*128; idx += 256) {
        int c = idx >> 7, ff = idx & 127;
        W1aT[c][ff] = W1[ff*137 + c];
    }
    __syncthreads();
    int wave = threadIdx.x >> 6, lane = threadIdx.x & 63;
    int t0b = xcd_swz(blockIdx.x, gridDim.x) * 4;
    {
        int t = t0b + wave;
        float wlo[9], whi[9];
#pragma unroll
        for (int c = 0; c < 9; ++c) { wlo[c] = W1aT[c][lane]; whi[c] = W1aT[c][64+lane]; }
        const float4* g4 = (const float4*)geo_s;
        float4 s0 = g4[t*3+0], s1 = g4[t*3+1], s2 = g4[t*3+2];
        float b1lo = b1[lane],            b1hi = b1[64+lane];
        float ylo  = Y[(size_t)t*H+lane], yhi  = Y[(size_t)t*H+64+lane];
        float accLo = 0.f, accHi = 0.f;
#pragma unroll
        for (int e = 0; e < KNN_K; ++e) {
            int tg = nbr[t*KNN_K + e];
            float4 t0 = g4[tg*3+0], t1 = g4[tg*3+1], t2 = g4[tg*3+2];
            float r0 = s0.x-t0.x, r1 = s0.y-t0.y, r2 = s0.z-t0.z, r3 = s0.w-t0.w;
            float r4 = s1.x-t1.x, r5 = s1.y-t1.y, r6 = s1.z-t1.z, r7 = s1.w-t1.w;
            float r8 = s2.x-t2.x;
            float gLo = b1lo;
            gLo = fmaf(wlo[0], r0, gLo); gLo = fmaf(wlo[1], r1, gLo); gLo = fmaf(wlo[2], r2, gLo);
            gLo = fmaf(wlo[3], r3, gLo); gLo = fmaf(wlo[4], r4, gLo);
            gLo = fmaf(wlo[5], r5, gLo); gLo = fmaf(wlo[6], r6, gLo);
            gLo = fmaf(wlo[7], r7, gLo); gLo = fmaf(wlo[8], r8, gLo);
            float gHi = b1hi;
            gHi = fmaf(whi[0], r0, gHi); gHi = fmaf(whi[1], r1, gHi); gHi = fmaf(whi[2], r2, gHi);
            gHi = fmaf(whi[3], r3, gHi); gHi = fmaf(whi[4], r4, gHi);
            gHi = fmaf(whi[5], r5, gHi); gHi = fmaf(whi[6], r6, gHi);
            gHi = fmaf(whi[7], r7, gHi); gHi = fmaf(whi[8], r8, gHi);
            accLo += fmaxf(gLo + ylo - Y[(size_t)tg*H + lane], 0.f);
            accHi += fmaxf(gHi + yhi - Y[(size_t)tg*H + 64 + lane], 0.f);
        }
        Srow[wave][lane]    = accLo;
        Srow[wave][64+lane] = accHi;
    }
    __syncthreads();
    int f = threadIdx.x & 127, half = threadIdx.x >> 7;
    float base = b2[f] * (float)KNN_K;
    float a0 = base, a1 = base;
    const int r0_ = half * 2;
#pragma unroll
    for (int c4 = 0; c4 < 32; ++c4) {
        float4 w = *(const float4*)&WTg[c4*512 + f*4];
        float4 v0 = ((const float4*)Srow[r0_+0])[c4];
        float4 v1 = ((const float4*)Srow[r0_+1])[c4];
        a0 = fmaf(w.x, v0.x, a0); a0 = fmaf(w.y, v0.y, a0);
        a0 = fmaf(w.z, v0.z, a0); a0 = fmaf(w.w, v0.w, a0);
        a1 = fmaf(w.x, v1.x, a1); a1 = fmaf(w.y, v1.y, a1);
        a1 = fmaf(w.z, v1.z, a1); a1 = fmaf(w.w, v1.w, a1);
    }
    if (!last) {
        X[(size_t)(t0b+r0_+0)*H + f] = a0;
        X[(size_t)(t0b+r0_+1)*H + f] = a1;
    } else {
        float wf = Wf[f];
        float p0 = a0*wf, p1 = a1*wf;
#pragma unroll
        for (int off = 32; off >= 1; off >>= 1) {
            p0 += __shfl_xor(p0, off);
            p1 += __shfl_xor(p1, off);
        }
        if (lane == 0) { fpart[wave][0] = p0; fpart[wave][1] = p1; }
        __syncthreads();
        if (threadIdx.x < 4) {
            int rr = threadIdx.x;
            int h = rr >> 1, j = rr & 1;
            float z = fpart[2*h][j] + fpart[2*h+1][j] + bf[0];
            out[oid[t0b + h*2 + j]] = 1.0f / (1.0f + expf(-z));
        }
    }
}

extern "C" void kernel_launch(void* const* d_in, const int* in_sizes, int n_in,
                              void* d_out, int out_size, void* d_ws, size_t ws_size,
                              hipStream_t stream) {
    (void)in_sizes; (void)n_in; (void)out_size; (void)ws_size;
    const float* pts   = (const float*)d_in[0];
    const int*   tris  = (const int*)d_in[1];
    const float* probs = (const float*)d_in[2];
    const float* W1[3] = {(const float*)d_in[3],  (const float*)d_in[7],  (const float*)d_in[11]};
    const float* b1[3] = {(const float*)d_in[4],  (const float*)d_in[8],  (const float*)d_in[12]};
    const float* W2[3] = {(const float*)d_in[5],  (const float*)d_in[9],  (const float*)d_in[13]};
    const float* b2[3] = {(const float*)d_in[6],  (const float*)d_in[10], (const float*)d_in[14]};
    const float* Wf = (const float*)d_in[15];
    const float* bf = (const float*)d_in[16];
    float* out = (float*)d_out;

    char* ws = (char*)d_ws;
    float*    geo  = (float*)(ws + WS_GEO);
    float4*   bq   = (float4*)(ws + WS_BQ);
    int*      nbr  = (int*)(ws + WS_NBR);
    float*    rs   = (float*)(ws + WS_RS);
    float*    WTg  = (float*)(ws + WS_WT);
    unsigned* mm   = (unsigned*)(ws + WS_MM);
    unsigned* cst  = (unsigned*)(ws + WS_CSTART);
    unsigned* cptr = (unsigned*)(ws + WS_CPTR);
    unsigned* hist = (unsigned*)(ws + WS_HIST);
    int*      cid  = (int*)(ws + WS_CID);
    int*      cso  = (int*)(ws + WS_CSORT);
    int*      oid  = (int*)(ws + WS_OID);
    float4*   bqs  = (float4*)(ws + WS_BQS);
    float*    ps   = (float*)(ws + WS_PS);
    float*    geos = (float*)(ws + WS_GEOS);
    float*    X    = (float*)(ws + WS_X);
    float*    Y    = (float*)(ws + WS_Y);

    grid_init_kernel<<<16, 256, 0, stream>>>(hist, mm);
    geom_kernel<<<(T_TRI+255)/256, 256, 0, stream>>>(pts, tris, geo, bq, mm);
    cellhist_kernel<<<(T_TRI+255)/256, 256, 0, stream>>>(bq, mm, cid, hist);
    prefix_kernel<<<1, 1024, 0, stream>>>(hist, cst, cptr);
    scatter_kernel<<<(T_TRI+255)/256, 256, 0, stream>>>(bq, cid, geo, probs, cptr, bqs, oid, cso, geos, ps);
    knn_grid_kernel<<<T_TRI/4, 256, 0, stream>>>(bqs, oid, cso, cst, mm, nbr);
    rowsum_kernel<<<1, 128, 0, stream>>>(W1[0], rs);
    wtrans_kernel<<<dim3(128,5), 128, 0, stream>>>(W1[1], W1[2], W2[0], W2[1], W2[2], WTg);
    y0_kernel<<<(T_TRI*H)/256, 256, 0, stream>>>(ps, rs, Y);
    for (int l = 0; l < 3; ++l) {
        if (l > 0)
            dense_kernel<<<T_TRI/DTPB, 128, 0, stream>>>(X, WTg + (size_t)(l-1)*16384, Y);
        edgefused_kernel<<<T_TRI/4, 256, 0, stream>>>(Y, geos, nbr, W1[l], b1[l],
                                                      WTg + (size_t)(2+l)*16384, b2[l], X,
                                                      Wf, bf, out, oid, (l == 2) ? 1 : 0);
    }
}

// Round 16
// 335.284 us; speedup vs baseline: 2.3064x; 1.3912x over previous
//
#include <hip/hip_runtime.h>
#include <math.h>

#define T_TRI 20000
#define KNN_K 20
#define H     128

// ---------------- workspace layout (bytes) ----------------
#define WS_GEO    0                       // 960KB (original-space geo)
#define WS_BQ     (1u<<20)                // 320KB
#define WS_NBR    (2u<<20)                // 1.6MB (sorted-space neighbor lists)
#define WS_RS     (4u<<20)                // 512B
#define WS_WT     ((4u<<20)+4096)         // 320KB
#define WS_MM     (5u<<20)                // 64B
#define WS_CSTART ((5u<<20)+64)           // 4097 u32
#define WS_CPTR   ((5u<<20)+(32u<<10))    // 4096 u32
#define WS_HIST   ((5u<<20)+(64u<<10))    // 4096 u32
#define WS_CID    ((5u<<20)+(128u<<10))   // 20000 i32
#define WS_CSORT  ((5u<<20)+(256u<<10))   // 20000 i32
#define WS_OID    ((5u<<20)+(384u<<10))   // 20000 i32
#define WS_BQS    ((5u<<20)+(512u<<10))   // 320KB
#define WS_WA     ((5u<<20)+(840u<<10))   // 3*9*128 f32 = 13.8KB
#define WS_PS     (6u<<20)                // 80KB (probs_s)
#define WS_GEOS   (7u<<20)                // 960KB (sorted-space geo)
#define WS_X      (9u<<20)
#define WS_Y      (20u<<20)               // Z buffer

__device__ __forceinline__ float readlane_f(float v, int l) {
    return __uint_as_float(__builtin_amdgcn_readlane(__float_as_uint(v), l));
}
// order-preserving float<->uint (for atomicMin/Max on floats)
__device__ __forceinline__ unsigned encf(float f) {
    unsigned u = __float_as_uint(f);
    return (u & 0x80000000u) ? ~u : (u | 0x80000000u);
}
__device__ __forceinline__ float decf(unsigned e) {
    unsigned u = (e & 0x80000000u) ? (e & 0x7FFFFFFFu) : ~e;
    return __uint_as_float(u);
}
// m204 bijective XCD swizzle (kept from R15: neutral-to-positive, aligns
// producer/consumer row-chunks on the same XCD L2).
__device__ __forceinline__ int xcd_swz(int bid, int nwg) {
    int q = nwg >> 3, rm = nwg & 7;
    int x = bid & 7, idx = bid >> 3;
    return (x < rm) ? x*(q+1) + idx : rm*(q+1) + (x-rm)*q + idx;
}

// ---------------- init: zero histogram, minmax sentinels ----------------
__global__ void grid_init_kernel(unsigned* __restrict__ hist, unsigned* __restrict__ mm) {
    int i = blockIdx.x * 256 + threadIdx.x;
    if (i < 4096) hist[i] = 0u;
    if (i < 3) mm[i] = 0xFFFFFFFFu;          // mins (uint-encoded)
    if (i >= 3 && i < 6) mm[i] = 0u;         // maxs
}

// ---------------- geometry (+ bary AABB via wave-reduced atomics) ----------------
__global__ void geom_kernel(const float* __restrict__ pts, const int* __restrict__ tris,
                            float* __restrict__ geo, float4* __restrict__ bq,
                            unsigned* __restrict__ mm) {
    int t = blockIdx.x * blockDim.x + threadIdx.x;
    int lane = threadIdx.x & 63;
    bool act = (t < T_TRI);
    int tt = act ? t : 0;
    int i0 = tris[3*tt], i1 = tris[3*tt+1], i2 = tris[3*tt+2];
    float ax = pts[3*i0], ay = pts[3*i0+1], az = pts[3*i0+2];
    float bx = pts[3*i1], by = pts[3*i1+1], bz = pts[3*i1+2];
    float cx = pts[3*i2], cy = pts[3*i2+1], cz = pts[3*i2+2];
    float e0x = ax-bx, e0y = ay-by, e0z = az-bz;   // e_ij
    float e1x = ax-cx, e1y = ay-cy, e1z = az-cz;   // e_ik
    float e2x = bx-cx, e2y = by-cy, e2z = bz-cz;   // e_jk
    float mnx = fminf(fminf(e0x,e1x),e2x), mny = fminf(fminf(e0y,e1y),e2y), mnz = fminf(fminf(e0z,e1z),e2z);
    float mxx = fmaxf(fmaxf(e0x,e1x),e2x), mxy = fmaxf(fmaxf(e0y,e1y),e2y), mxz = fmaxf(fmaxf(e0z,e1z),e2z);
    float gx = (ax+bx+cx)*(1.0f/3.0f), gy = (ay+by+cy)*(1.0f/3.0f), gz = (az+bz+cz)*(1.0f/3.0f);
    float sq = (gx*gx + gy*gy) + gz*gz;
    if (act) {
        float* g = geo + (size_t)t*12;
        g[0]=mnx; g[1]=mny; g[2]=mnz; g[3]=mxx; g[4]=mxy; g[5]=mxz;
        g[6]=gx;  g[7]=gy;  g[8]=gz;  g[9]=0.f; g[10]=0.f; g[11]=0.f;
        bq[t] = make_float4(gx, gy, gz, sq);
    }
    unsigned n0 = act ? encf(gx) : 0xFFFFFFFFu;
    unsigned n1 = act ? encf(gy) : 0xFFFFFFFFu;
    unsigned n2 = act ? encf(gz) : 0xFFFFFFFFu;
    unsigned x0 = act ? encf(gx) : 0u;
    unsigned x1 = act ? encf(gy) : 0u;
    unsigned x2 = act ? encf(gz) : 0u;
#pragma unroll
    for (int off = 32; off >= 1; off >>= 1) {
        n0 = min(n0, (unsigned)__shfl_xor((int)n0, off));
        n1 = min(n1, (unsigned)__shfl_xor((int)n1, off));
        n2 = min(n2, (unsigned)__shfl_xor((int)n2, off));
        x0 = max(x0, (unsigned)__shfl_xor((int)x0, off));
        x1 = max(x1, (unsigned)__shfl_xor((int)x1, off));
        x2 = max(x2, (unsigned)__shfl_xor((int)x2, off));
    }
    if (lane == 0) {
        atomicMin(&mm[0], n0); atomicMin(&mm[1], n1); atomicMin(&mm[2], n2);
        atomicMax(&mm[3], x0); atomicMax(&mm[4], x1); atomicMax(&mm[5], x2);
    }
}

// ---------------- cell assignment + histogram ----------------
__global__ void cellhist_kernel(const float4* __restrict__ bq, const unsigned* __restrict__ mm,
                                int* __restrict__ cellid, unsigned* __restrict__ hist) {
    int t = blockIdx.x * 256 + threadIdx.x;
    if (t >= T_TRI) return;
    float mnx = decf(mm[0]), mny = decf(mm[1]), mnz = decf(mm[2]);
    float mxx = decf(mm[3]), mxy = decf(mm[4]), mxz = decf(mm[5]);
    float ihx = 16.f / fmaxf(mxx-mnx, 1e-30f);
    float ihy = 16.f / fmaxf(mxy-mny, 1e-30f);
    float ihz = 16.f / fmaxf(mxz-mnz, 1e-30f);
    float4 b = bq[t];
    int ix = min(15, max(0, (int)((b.x-mnx)*ihx)));
    int iy = min(15, max(0, (int)((b.y-mny)*ihy)));
    int iz = min(15, max(0, (int)((b.z-mnz)*ihz)));
    int c = (ix<<8) | (iy<<4) | iz;
    cellid[t] = c;
    atomicAdd(&hist[c], 1u);
}

// ---------------- exclusive prefix over 4096 cells (1 block) ----------------
__global__ __launch_bounds__(1024) void prefix_kernel(const unsigned* __restrict__ hist,
                                                      unsigned* __restrict__ cellstart,
                                                      unsigned* __restrict__ cellptr) {
    __shared__ unsigned sbuf[1024];
    int tid = threadIdx.x;
    uint4 v = ((const uint4*)hist)[tid];
    unsigned mysum = v.x + v.y + v.z + v.w;
    sbuf[tid] = mysum;
    __syncthreads();
    for (int off = 1; off < 1024; off <<= 1) {
        unsigned add = (tid >= off) ? sbuf[tid - off] : 0u;
        __syncthreads();
        sbuf[tid] += add;
        __syncthreads();
    }
    unsigned excl = sbuf[tid] - mysum;
    unsigned p0 = excl, p1 = p0 + v.x, p2 = p1 + v.y, p3 = p2 + v.z;
    cellstart[4*tid+0] = p0; cellstart[4*tid+1] = p1;
    cellstart[4*tid+2] = p2; cellstart[4*tid+3] = p3;
    cellptr[4*tid+0] = p0; cellptr[4*tid+1] = p1;
    cellptr[4*tid+2] = p2; cellptr[4*tid+3] = p3;
    if (tid == 1023) cellstart[4096] = p3 + v.w;
}

// ---------------- scatter into cell-sorted order (+ relabeled geo/probs) ----------------
__global__ void scatter_kernel(const float4* __restrict__ bq, const int* __restrict__ cellid,
                               const float* __restrict__ geo, const float* __restrict__ probs,
                               unsigned* __restrict__ cellptr, float4* __restrict__ bqs,
                               int* __restrict__ oid, int* __restrict__ csort,
                               float* __restrict__ geo_s, float* __restrict__ probs_s) {
    int t = blockIdx.x * 256 + threadIdx.x;
    if (t >= T_TRI) return;
    int c = cellid[t];
    unsigned p = atomicAdd(&cellptr[c], 1u);
    bqs[p] = bq[t];
    oid[p]  = t;
    csort[p] = c;
    const float4* g4 = (const float4*)geo;
    float4* g4s = (float4*)geo_s;
    g4s[(size_t)p*3+0] = g4[(size_t)t*3+0];
    g4s[(size_t)p*3+1] = g4[(size_t)t*3+1];
    g4s[(size_t)p*3+2] = g4[(size_t)t*3+2];
    probs_s[p] = probs[t];
}

// ---------------- grid KNN: home-cell-first + per-cell min-dist bound pruning ----------------
// Scan the HOME cell first (seeds theta near-final for dense rows). Then for
// each window, evaluate candidate cells lane-parallel and DROP any cell whose
// geometric min-dist^2 to the query exceeds th + 1e-3 (true distance of every
// point in that cell > th strictly, since cell-assignment fp error ~1e-6 and
// the distance-formula error ~5e-6 are dwarfed by the 1e-3 slack -> exact).
// Sparse rows (th=INF after home) degrade to the full w=1 box. Distance
// formula, drain/insert logic, tie-break on ORIGINAL indices, sorted-index
// payload, and the stop bound are byte-identical to the R14/R15-passing kernels.
__global__ __launch_bounds__(256) void knn_grid_kernel(const float4* __restrict__ bqs,
        const int* __restrict__ oid, const int* __restrict__ csort,
        const unsigned* __restrict__ cellstart, const unsigned* __restrict__ mm,
        int* __restrict__ nbr) {
    int wave = threadIdx.x >> 6, lane = threadIdx.x & 63;
    int r = blockIdx.x * 4 + wave;
    float4 q = bqs[r];
    int myc = csort[r];
    int cx = (myc>>8)&15, cy = (myc>>4)&15, cz = myc&15;
    float mnx = decf(mm[0]), mny = decf(mm[1]), mnz = decf(mm[2]);
    float hx = (decf(mm[3]) - mnx) * (1.f/16.f);
    float hy = (decf(mm[4]) - mny) * (1.f/16.f);
    float hz = (decf(mm[5]) - mnz) * (1.f/16.f);
    float hmin = fminf(hx, fminf(hy, hz));

    float rd = INFINITY;
    int   ri = 0x7FF00000 | lane;     // distinct sentinels (orig-idx key)
    int   rk = lane;                  // sorted-idx payload
    float th = INFINITY;
    int   mi = 0x7FFFFFFF;

#define SCAN_RANGE(RS, RE)                                                          \
    for (unsigned base = (RS); base < (RE); base += 64u) {                          \
        unsigned k = base + (unsigned)lane;                                         \
        bool kv = (k < (RE));                                                       \
        float4 c4 = kv ? bqs[k] : make_float4(INFINITY,INFINITY,INFINITY,INFINITY); \
        int ov = kv ? oid[k] : 0x7FFFFFFF;                                          \
        float dot = fmaf(q.z, c4.z, fmaf(q.y, c4.y, q.x*c4.x));                     \
        float d = (q.w + c4.w) - 2.0f*dot;                                          \
        unsigned long long bal = __ballot(kv && (d <= th));                         \
        while (bal) {                                                               \
            int src = __ffsll(bal) - 1; bal &= bal - 1;                             \
            float dc = readlane_f(d, src);                                          \
            int   jc = __builtin_amdgcn_readlane(ov, src);                          \
            int   kc = (int)base + src;                                             \
            if ((dc < th) || (dc == th && jc < mi)) {                               \
                bool less = (rd < dc) || (rd == dc && ri < jc);                     \
                int pos = __popcll(__ballot(less) & 0x1FFFFFull);                   \
                float sd = __shfl_up(rd, 1);                                        \
                int   si = __shfl_up(ri, 1);                                        \
                int   sk = __shfl_up(rk, 1);                                        \
                if (lane < 21) {                                                    \
                    if (lane == pos)      { rd = dc; ri = jc; rk = kc; }            \
                    else if (lane > pos)  { rd = sd; ri = si; rk = sk; }            \
                }                                                                   \
                th = readlane_f(rd, 20);                                            \
                mi = __builtin_amdgcn_readlane(ri, 20);                             \
            }                                                                       \
        }                                                                           \
    }

// per-lane cell min-dist^2 bound vs query; conservative skip (1e-3 slack)
#define CELL_BOUND_OK(EX, EY, EZ)                                                   \
    ({  float cl0 = fmaf((float)(EX), hx, mnx);                                     \
        float cm0 = fmaf((float)(EY), hy, mny);                                     \
        float cn0 = fmaf((float)(EZ), hz, mnz);                                     \
        float ddx = fmaxf(fmaxf(cl0 - q.x, q.x - (cl0 + hx)), 0.f);                 \
        float ddy = fmaxf(fmaxf(cm0 - q.y, q.y - (cm0 + hy)), 0.f);                 \
        float ddz = fmaxf(fmaxf(cn0 - q.z, q.z - (cn0 + hz)), 0.f);                 \
        float bnd = fmaf(ddx, ddx, fmaf(ddy, ddy, ddz*ddz));                        \
        (bnd <= th + 1e-3f); })

    // home cell first
    {
        unsigned hs = cellstart[myc], he = cellstart[myc + 1];
        SCAN_RANGE(hs, he)
    }

    for (int w = 1; w <= 15; ++w) {
        if (w == 1) {
            // 27-cell box minus home, one lane per cell, bound-filtered
            int i = lane;
            bool val = (i < 27) && (i != 13);
            int ii = (i < 27) ? i : 0;
            int dz = ii % 3 - 1, dy = (ii / 3) % 3 - 1, dx = ii / 9 - 1;
            int ex = cx + dx, ey = cy + dy, ez = cz + dz;
            val = val && ex >= 0 && ex < 16 && ey >= 0 && ey < 16 && ez >= 0 && ez < 16;
            int cell = (ex<<8) | (ey<<4) | ez;
            unsigned cs = 0u, ce = 0u;
            if (val) { cs = cellstart[cell]; ce = cellstart[cell+1]; }
            val = val && (cs < ce);
            if (val) val = CELL_BOUND_OK(ex, ey, ez);
            unsigned long long cm = __ballot(val);
            while (cm) {
                int cl = __ffsll(cm) - 1; cm &= cm - 1;
                unsigned s0 = (unsigned)__builtin_amdgcn_readlane((int)cs, cl);
                unsigned e0 = (unsigned)__builtin_amdgcn_readlane((int)ce, cl);
                SCAN_RANGE(s0, e0)
            }
        } else {
            int W = 2*w + 1, W2 = W*W, tot = W*W2;
            for (int b0 = 0; b0 < tot; b0 += 64) {
                int i = b0 + lane;
                bool val = (i < tot);
                int ii = val ? i : 0;
                int dz = ii % W - w, dy = (ii / W) % W - w, dx = ii / W2 - w;
                int cheb = max(abs(dx), max(abs(dy), abs(dz)));
                val = val && (cheb == w);
                int ex = cx + dx, ey = cy + dy, ez = cz + dz;
                val = val && ex >= 0 && ex < 16 && ey >= 0 && ey < 16 && ez >= 0 && ez < 16;
                int cell = (ex<<8) | (ey<<4) | ez;
                unsigned cs = 0u, ce = 0u;
                if (val) { cs = cellstart[cell]; ce = cellstart[cell+1]; }
                val = val && (cs < ce);
                if (val) val = CELL_BOUND_OK(ex, ey, ez);
                unsigned long long cm = __ballot(val);
                while (cm) {
                    int cl = __ffsll(cm) - 1; cm &= cm - 1;
                    unsigned s0 = (unsigned)__builtin_amdgcn_readlane((int)cs, cl);
                    unsigned e0 = (unsigned)__builtin_amdgcn_readlane((int)ce, cl);
                    SCAN_RANGE(s0, e0)
                }
            }
        }
        bool covered = (cx-w <= 0) && (cx+w >= 15) && (cy-w <= 0) && (cy+w >= 15)
                    && (cz-w <= 0) && (cz+w >= 15);
        if (covered) break;
        float bd = (float)w * hmin - 1e-3f;
        if (bd > 0.f && th < bd*bd) break;
    }
#undef CELL_BOUND_OK
#undef SCAN_RANGE
    // lane l holds rank-l entry; rank 0 = self, dropped; emit SORTED index
    if (lane >= 1 && lane < 21) nbr[r*KNN_K + lane - 1] = rk;
}

// ---------------- rowsum + W1a transpose (once, tiny) ----------------
__global__ void rowsum_kernel(const float* __restrict__ W1, float* __restrict__ rs) {
    int f = threadIdx.x;
    float s = 0.f;
    for (int c = 0; c < H; ++c) s += W1[f*137 + 9 + c];
    rs[f] = s;
}
// WA[m][c][f] = W1_m[f][c], c in [0,9)
__global__ void watrans_kernel(const float* __restrict__ W10, const float* __restrict__ W11,
                               const float* __restrict__ W12, float* __restrict__ WA) {
    int f = threadIdx.x, c = blockIdx.x, m = blockIdx.y;
    const float* W = (m == 0) ? W10 : (m == 1) ? W11 : W12;
    WA[m*9*128 + c*128 + f] = W[f*137 + c];
}

// ---------------- layer-0 Z: Z0[t][f] = p_s[t]*rs[f] + sum_c WA0[c][f]*geo9_s[t][c] ----------------
// (Z = W1b.x + W1a.geo9 hoisted out of the edge loop: pre = (Z_s + b1) - Z_t.)
__global__ void y0_kernel(const float* __restrict__ ps, const float* __restrict__ rs,
                          const float* __restrict__ WA0, const float* __restrict__ geo_s,
                          float* __restrict__ Z) {
    int bid = xcd_swz(blockIdx.x, gridDim.x);
    int tid = bid * 256 + threadIdx.x;   // over T*H
    int t = tid >> 7, f = tid & 127;
    float acc = ps[t] * rs[f];
#pragma unroll
    for (int c = 0; c < 9; ++c)
        acc = fmaf(WA0[c*128 + f], geo_s[(size_t)t*12 + c], acc);
    Z[tid] = acc;
}

// ---------------- weight pre-transpose (once, tiny) ----------------
__global__ void wtrans_kernel(const float* __restrict__ W11, const float* __restrict__ W12,
                              const float* __restrict__ W20, const float* __restrict__ W21,
                              const float* __restrict__ W22, float* __restrict__ WTg) {
    int f = threadIdx.x, c = blockIdx.x, m = blockIdx.y;
    const float* W; int stride, col0;
    if      (m == 0) { W = W11; stride = 137; col0 = 9; }
    else if (m == 1) { W = W12; stride = 137; col0 = 9; }
    else if (m == 2) { W = W20; stride = 128; col0 = 0; }
    else if (m == 3) { W = W21; stride = 128; col0 = 0; }
    else             { W = W22; stride = 128; col0 = 0; }
    WTg[m*16384 + (c>>2)*512 + f*4 + (c&3)] = W[f*stride + col0 + c];
}

// ---------------- dense: Z[t][f] = X[t]@W1b^T + geo9[t]@W1a^T (epilogue) ----------------
#define DTPB 16
__global__ __launch_bounds__(128) void dense_kernel(const float* __restrict__ A, const float* __restrict__ WTg,
                             const float* __restrict__ WA, const float* __restrict__ geo_s,
                             float* __restrict__ C) {
    __shared__ float Ar[8][128];
    __shared__ float WAs[9][128];
    int f = threadIdx.x;
#pragma unroll
    for (int c = 0; c < 9; ++c) WAs[c][f] = WA[c*128 + f];
    int t0 = xcd_swz(blockIdx.x, gridDim.x) * DTPB;
    for (int tt = 0; tt < DTPB; tt += 8) {
        __syncthreads();
#pragma unroll
        for (int j = 0; j < 8; ++j) Ar[j][f] = A[(size_t)(t0+tt+j)*H + f];
        __syncthreads();
        float a0 = 0.f, a1 = 0.f, a2 = 0.f, a3 = 0.f;
        float a4_ = 0.f, a5 = 0.f, a6 = 0.f, a7 = 0.f;
#pragma unroll
        for (int c4 = 0; c4 < 32; ++c4) {
            float4 w = *(const float4*)&WTg[c4*512 + f*4];
#define DROW(J, ACC)                                                        \
            {                                                               \
                float4 v = ((const float4*)Ar[J])[c4];                      \
                ACC = fmaf(w.x, v.x, ACC); ACC = fmaf(w.y, v.y, ACC);       \
                ACC = fmaf(w.z, v.z, ACC); ACC = fmaf(w.w, v.w, ACC);       \
            }
            DROW(0, a0) DROW(1, a1) DROW(2, a2) DROW(3, a3)
            DROW(4, a4_) DROW(5, a5) DROW(6, a6) DROW(7, a7)
#undef DROW
        }
        // geo9 @ W1a^T epilogue (broadcast loads, 9 fma per row)
#pragma unroll
        for (int c = 0; c < 9; ++c) {
            float w = WAs[c][f];
            a0  = fmaf(w, geo_s[(size_t)(t0+tt+0)*12 + c], a0);
            a1  = fmaf(w, geo_s[(size_t)(t0+tt+1)*12 + c], a1);
            a2  = fmaf(w, geo_s[(size_t)(t0+tt+2)*12 + c], a2);
            a3  = fmaf(w, geo_s[(size_t)(t0+tt+3)*12 + c], a3);
            a4_ = fmaf(w, geo_s[(size_t)(t0+tt+4)*12 + c], a4_);
            a5  = fmaf(w, geo_s[(size_t)(t0+tt+5)*12 + c], a5);
            a6  = fmaf(w, geo_s[(size_t)(t0+tt+6)*12 + c], a6);
            a7  = fmaf(w, geo_s[(size_t)(t0+tt+7)*12 + c], a7);
        }
        C[(size_t)(t0+tt+0)*H + f] = a0;
        C[(size_t)(t0+tt+1)*H + f] = a1;
        C[(size_t)(t0+tt+2)*H + f] = a2;
        C[(size_t)(t0+tt+3)*H + f] = a3;
        C[(size_t)(t0+tt+4)*H + f] = a4_;
        C[(size_t)(t0+tt+5)*H + f] = a5;
        C[(size_t)(t0+tt+6)*H + f] = a6;
        C[(size_t)(t0+tt+7)*H + f] = a7;
    }
}

// ---------------- fused edge + W2 (+ head): edge body is now 1 gather + 3 ops ----------------
// pre = (Z_s + b1) - Z_tgt; S = sum_e relu(pre). The W1a matvec and geo
// gathers are hoisted into Z (dense/y0). W2 phase and head unchanged.
__global__ __launch_bounds__(256) void edgefused_kernel(const float* __restrict__ Z,
                            const int* __restrict__ nbr,
                            const float* __restrict__ b1, const float* __restrict__ WTg,
                            const float* __restrict__ b2, float* __restrict__ X,
                            const float* __restrict__ Wf, const float* __restrict__ bf,
                            float* __restrict__ out, const int* __restrict__ oid, int last) {
    __shared__ float Srow[4][128];
    __shared__ float fpart[4][2];
    int wave = threadIdx.x >> 6, lane = threadIdx.x & 63;
    int t0b = xcd_swz(blockIdx.x, gridDim.x) * 4;
    {
        int t = t0b + wave;
        float zsLo = Z[(size_t)t*H + lane]      + b1[lane];
        float zsHi = Z[(size_t)t*H + 64 + lane] + b1[64 + lane];
        float accLo = 0.f, accHi = 0.f;
#pragma unroll
        for (int e = 0; e < KNN_K; ++e) {
            int tg = nbr[t*KNN_K + e];
            accLo += fmaxf(zsLo - Z[(size_t)tg*H + lane],      0.f);
            accHi += fmaxf(zsHi - Z[(size_t)tg*H + 64 + lane], 0.f);
        }
        Srow[wave][lane]    = accLo;
        Srow[wave][64+lane] = accHi;
    }
    __syncthreads();
    int f = threadIdx.x & 127, half = threadIdx.x >> 7;
    float base = b2[f] * (float)KNN_K;
    float a0 = base, a1 = base;
    const int r0_ = half * 2;
#pragma unroll
    for (int c4 = 0; c4 < 32; ++c4) {
        float4 w = *(const float4*)&WTg[c4*512 + f*4];
        float4 v0 = ((const float4*)Srow[r0_+0])[c4];
        float4 v1 = ((const float4*)Srow[r0_+1])[c4];
        a0 = fmaf(w.x, v0.x, a0); a0 = fmaf(w.y, v0.y, a0);
        a0 = fmaf(w.z, v0.z, a0); a0 = fmaf(w.w, v0.w, a0);
        a1 = fmaf(w.x, v1.x, a1); a1 = fmaf(w.y, v1.y, a1);
        a1 = fmaf(w.z, v1.z, a1); a1 = fmaf(w.w, v1.w, a1);
    }
    if (!last) {
        X[(size_t)(t0b+r0_+0)*H + f] = a0;
        X[(size_t)(t0b+r0_+1)*H + f] = a1;
    } else {
        float wf = Wf[f];
        float p0 = a0*wf, p1 = a1*wf;
#pragma unroll
        for (int off = 32; off >= 1; off >>= 1) {
            p0 += __shfl_xor(p0, off);
            p1 += __shfl_xor(p1, off);
        }
        if (lane == 0) { fpart[wave][0] = p0; fpart[wave][1] = p1; }
        __syncthreads();
        if (threadIdx.x < 4) {
            int rr = threadIdx.x;
            int h = rr >> 1, j = rr & 1;
            float z = fpart[2*h][j] + fpart[2*h+1][j] + bf[0];
            out[oid[t0b + h*2 + j]] = 1.0f / (1.0f + expf(-z));
        }
    }
}

extern "C" void kernel_launch(void* const* d_in, const int* in_sizes, int n_in,
                              void* d_out, int out_size, void* d_ws, size_t ws_size,
                              hipStream_t stream) {
    (void)in_sizes; (void)n_in; (void)out_size; (void)ws_size;
    const float* pts   = (const float*)d_in[0];
    const int*   tris  = (const int*)d_in[1];
    const float* probs = (const float*)d_in[2];
    const float* W1[3] = {(const float*)d_in[3],  (const float*)d_in[7],  (const float*)d_in[11]};
    const float* b1[3] = {(const float*)d_in[4],  (const float*)d_in[8],  (const float*)d_in[12]};
    const float* W2[3] = {(const float*)d_in[5],  (const float*)d_in[9],  (const float*)d_in[13]};
    const float* b2[3] = {(const float*)d_in[6],  (const float*)d_in[10], (const float*)d_in[14]};
    const float* Wf = (const float*)d_in[15];
    const float* bf = (const float*)d_in[16];
    float* out = (float*)d_out;

    char* ws = (char*)d_ws;
    float*    geo  = (float*)(ws + WS_GEO);
    float4*   bq   = (float4*)(ws + WS_BQ);
    int*      nbr  = (int*)(ws + WS_NBR);
    float*    rs   = (float*)(ws + WS_RS);
    float*    WTg  = (float*)(ws + WS_WT);
    unsigned* mm   = (unsigned*)(ws + WS_MM);
    unsigned* cst  = (unsigned*)(ws + WS_CSTART);
    unsigned* cptr = (unsigned*)(ws + WS_CPTR);
    unsigned* hist = (unsigned*)(ws + WS_HIST);
    int*      cid  = (int*)(ws + WS_CID);
    int*      cso  = (int*)(ws + WS_CSORT);
    int*      oid  = (int*)(ws + WS_OID);
    float4*   bqs  = (float4*)(ws + WS_BQS);
    float*    WA   = (float*)(ws + WS_WA);
    float*    ps   = (float*)(ws + WS_PS);
    float*    geos = (float*)(ws + WS_GEOS);
    float*    X    = (float*)(ws + WS_X);
    float*    Z    = (float*)(ws + WS_Y);

    grid_init_kernel<<<16, 256, 0, stream>>>(hist, mm);
    geom_kernel<<<(T_TRI+255)/256, 256, 0, stream>>>(pts, tris, geo, bq, mm);
    cellhist_kernel<<<(T_TRI+255)/256, 256, 0, stream>>>(bq, mm, cid, hist);
    prefix_kernel<<<1, 1024, 0, stream>>>(hist, cst, cptr);
    scatter_kernel<<<(T_TRI+255)/256, 256, 0, stream>>>(bq, cid, geo, probs, cptr, bqs, oid, cso, geos, ps);
    knn_grid_kernel<<<T_TRI/4, 256, 0, stream>>>(bqs, oid, cso, cst, mm, nbr);
    rowsum_kernel<<<1, 128, 0, stream>>>(W1[0], rs);
    watrans_kernel<<<dim3(9,3), 128, 0, stream>>>(W1[0], W1[1], W1[2], WA);
    wtrans_kernel<<<dim3(128,5), 128, 0, stream>>>(W1[1], W1[2], W2[0], W2[1], W2[2], WTg);
    y0_kernel<<<(T_TRI*H)/256, 256, 0, stream>>>(ps, rs, WA, geos, Z);
    for (int l = 0; l < 3; ++l) {
        if (l > 0)
            dense_kernel<<<T_TRI/DTPB, 128, 0, stream>>>(X, WTg + (size_t)(l-1)*16384,
                                                         WA + (size_t)l*9*128, geos, Z);
        edgefused_kernel<<<T_TRI/4, 256, 0, stream>>>(Z, nbr, b1[l],
                                                      WTg + (size_t)(2+l)*16384, b2[l], X,
                                                      Wf, bf, out, oid, (l == 2) ? 1 : 0);
    }
}

// Round 17
// 279.540 us; speedup vs baseline: 2.7664x; 1.1994x over previous
//
#include <hip/hip_runtime.h>
#include <math.h>

#define T_TRI 20000
#define KNN_K 20
#define H     128

// ---------------- workspace layout (bytes) ----------------
#define WS_GEO    0                       // 960KB (original-space geo)
#define WS_BQ     (1u<<20)                // 320KB
#define WS_NBR    (2u<<20)                // 1.6MB (sorted-space neighbor lists)
#define WS_RS     (4u<<20)                // 512B
#define WS_MT     ((4u<<20)+4096)         // MTg: 2*16384 f32 = 128KB (folded GEMMs)
#define WS_WV     ((4u<<20)+4096+(256u<<10)) // v0,v1,wf2,cst: 385 f32
#define WS_MM     (5u<<20)                // 64B
#define WS_CSTART ((5u<<20)+64)           // 4097 u32
#define WS_CPTR   ((5u<<20)+(32u<<10))    // 4096 u32
#define WS_HIST   ((5u<<20)+(64u<<10))    // 4096 u32
#define WS_CID    ((5u<<20)+(128u<<10))   // 20000 i32
#define WS_CSORT  ((5u<<20)+(256u<<10))   // 20000 i32
#define WS_OID    ((5u<<20)+(384u<<10))   // 20000 i32
#define WS_BQS    ((5u<<20)+(512u<<10))   // 320KB
#define WS_WA     ((5u<<20)+(840u<<10))   // 3*9*128 f32
#define WS_PS     (6u<<20)                // 80KB (probs_s)
#define WS_GEOS   (7u<<20)                // 960KB (sorted-space geo)
#define WS_ZB     (9u<<20)                // Z ping buffer
#define WS_ZA     (20u<<20)               // Z pong buffer

__device__ __forceinline__ float readlane_f(float v, int l) {
    return __uint_as_float(__builtin_amdgcn_readlane(__float_as_uint(v), l));
}
// order-preserving float<->uint (for atomicMin/Max on floats)
__device__ __forceinline__ unsigned encf(float f) {
    unsigned u = __float_as_uint(f);
    return (u & 0x80000000u) ? ~u : (u | 0x80000000u);
}
__device__ __forceinline__ float decf(unsigned e) {
    unsigned u = (e & 0x80000000u) ? (e & 0x7FFFFFFFu) : ~e;
    return __uint_as_float(u);
}
// m204 bijective XCD swizzle (R15/R16: aligns producer/consumer row-chunks).
__device__ __forceinline__ int xcd_swz(int bid, int nwg) {
    int q = nwg >> 3, rm = nwg & 7;
    int x = bid & 7, idx = bid >> 3;
    return (x < rm) ? x*(q+1) + idx : rm*(q+1) + (x-rm)*q + idx;
}

// ---------------- init: zero histogram, minmax sentinels ----------------
__global__ void grid_init_kernel(unsigned* __restrict__ hist, unsigned* __restrict__ mm) {
    int i = blockIdx.x * 256 + threadIdx.x;
    if (i < 4096) hist[i] = 0u;
    if (i < 3) mm[i] = 0xFFFFFFFFu;          // mins (uint-encoded)
    if (i >= 3 && i < 6) mm[i] = 0u;         // maxs
}

// ---------------- geometry (+ bary AABB via wave-reduced atomics) ----------------
__global__ void geom_kernel(const float* __restrict__ pts, const int* __restrict__ tris,
                            float* __restrict__ geo, float4* __restrict__ bq,
                            unsigned* __restrict__ mm) {
    int t = blockIdx.x * blockDim.x + threadIdx.x;
    int lane = threadIdx.x & 63;
    bool act = (t < T_TRI);
    int tt = act ? t : 0;
    int i0 = tris[3*tt], i1 = tris[3*tt+1], i2 = tris[3*tt+2];
    float ax = pts[3*i0], ay = pts[3*i0+1], az = pts[3*i0+2];
    float bx = pts[3*i1], by = pts[3*i1+1], bz = pts[3*i1+2];
    float cx = pts[3*i2], cy = pts[3*i2+1], cz = pts[3*i2+2];
    float e0x = ax-bx, e0y = ay-by, e0z = az-bz;   // e_ij
    float e1x = ax-cx, e1y = ay-cy, e1z = az-cz;   // e_ik
    float e2x = bx-cx, e2y = by-cy, e2z = bz-cz;   // e_jk
    float mnx = fminf(fminf(e0x,e1x),e2x), mny = fminf(fminf(e0y,e1y),e2y), mnz = fminf(fminf(e0z,e1z),e2z);
    float mxx = fmaxf(fmaxf(e0x,e1x),e2x), mxy = fmaxf(fmaxf(e0y,e1y),e2y), mxz = fmaxf(fmaxf(e0z,e1z),e2z);
    float gx = (ax+bx+cx)*(1.0f/3.0f), gy = (ay+by+cy)*(1.0f/3.0f), gz = (az+bz+cz)*(1.0f/3.0f);
    float sq = (gx*gx + gy*gy) + gz*gz;
    if (act) {
        float* g = geo + (size_t)t*12;
        g[0]=mnx; g[1]=mny; g[2]=mnz; g[3]=mxx; g[4]=mxy; g[5]=mxz;
        g[6]=gx;  g[7]=gy;  g[8]=gz;  g[9]=0.f; g[10]=0.f; g[11]=0.f;
        bq[t] = make_float4(gx, gy, gz, sq);
    }
    unsigned n0 = act ? encf(gx) : 0xFFFFFFFFu;
    unsigned n1 = act ? encf(gy) : 0xFFFFFFFFu;
    unsigned n2 = act ? encf(gz) : 0xFFFFFFFFu;
    unsigned x0 = act ? encf(gx) : 0u;
    unsigned x1 = act ? encf(gy) : 0u;
    unsigned x2 = act ? encf(gz) : 0u;
#pragma unroll
    for (int off = 32; off >= 1; off >>= 1) {
        n0 = min(n0, (unsigned)__shfl_xor((int)n0, off));
        n1 = min(n1, (unsigned)__shfl_xor((int)n1, off));
        n2 = min(n2, (unsigned)__shfl_xor((int)n2, off));
        x0 = max(x0, (unsigned)__shfl_xor((int)x0, off));
        x1 = max(x1, (unsigned)__shfl_xor((int)x1, off));
        x2 = max(x2, (unsigned)__shfl_xor((int)x2, off));
    }
    if (lane == 0) {
        atomicMin(&mm[0], n0); atomicMin(&mm[1], n1); atomicMin(&mm[2], n2);
        atomicMax(&mm[3], x0); atomicMax(&mm[4], x1); atomicMax(&mm[5], x2);
    }
}

// ---------------- cell assignment + histogram ----------------
__global__ void cellhist_kernel(const float4* __restrict__ bq, const unsigned* __restrict__ mm,
                                int* __restrict__ cellid, unsigned* __restrict__ hist) {
    int t = blockIdx.x * 256 + threadIdx.x;
    if (t >= T_TRI) return;
    float mnx = decf(mm[0]), mny = decf(mm[1]), mnz = decf(mm[2]);
    float mxx = decf(mm[3]), mxy = decf(mm[4]), mxz = decf(mm[5]);
    float ihx = 16.f / fmaxf(mxx-mnx, 1e-30f);
    float ihy = 16.f / fmaxf(mxy-mny, 1e-30f);
    float ihz = 16.f / fmaxf(mxz-mnz, 1e-30f);
    float4 b = bq[t];
    int ix = min(15, max(0, (int)((b.x-mnx)*ihx)));
    int iy = min(15, max(0, (int)((b.y-mny)*ihy)));
    int iz = min(15, max(0, (int)((b.z-mnz)*ihz)));
    int c = (ix<<8) | (iy<<4) | iz;
    cellid[t] = c;
    atomicAdd(&hist[c], 1u);
}

// ---------------- exclusive prefix over 4096 cells (1 block) ----------------
__global__ __launch_bounds__(1024) void prefix_kernel(const unsigned* __restrict__ hist,
                                                      unsigned* __restrict__ cellstart,
                                                      unsigned* __restrict__ cellptr) {
    __shared__ unsigned sbuf[1024];
    int tid = threadIdx.x;
    uint4 v = ((const uint4*)hist)[tid];
    unsigned mysum = v.x + v.y + v.z + v.w;
    sbuf[tid] = mysum;
    __syncthreads();
    for (int off = 1; off < 1024; off <<= 1) {
        unsigned add = (tid >= off) ? sbuf[tid - off] : 0u;
        __syncthreads();
        sbuf[tid] += add;
        __syncthreads();
    }
    unsigned excl = sbuf[tid] - mysum;
    unsigned p0 = excl, p1 = p0 + v.x, p2 = p1 + v.y, p3 = p2 + v.z;
    cellstart[4*tid+0] = p0; cellstart[4*tid+1] = p1;
    cellstart[4*tid+2] = p2; cellstart[4*tid+3] = p3;
    cellptr[4*tid+0] = p0; cellptr[4*tid+1] = p1;
    cellptr[4*tid+2] = p2; cellptr[4*tid+3] = p3;
    if (tid == 1023) cellstart[4096] = p3 + v.w;
}

// ---------------- scatter into cell-sorted order (+ relabeled geo/probs) ----------------
__global__ void scatter_kernel(const float4* __restrict__ bq, const int* __restrict__ cellid,
                               const float* __restrict__ geo, const float* __restrict__ probs,
                               unsigned* __restrict__ cellptr, float4* __restrict__ bqs,
                               int* __restrict__ oid, int* __restrict__ csort,
                               float* __restrict__ geo_s, float* __restrict__ probs_s) {
    int t = blockIdx.x * 256 + threadIdx.x;
    if (t >= T_TRI) return;
    int c = cellid[t];
    unsigned p = atomicAdd(&cellptr[c], 1u);
    bqs[p] = bq[t];
    oid[p]  = t;
    csort[p] = c;
    const float4* g4 = (const float4*)geo;
    float4* g4s = (float4*)geo_s;
    g4s[(size_t)p*3+0] = g4[(size_t)t*3+0];
    g4s[(size_t)p*3+1] = g4[(size_t)t*3+1];
    g4s[(size_t)p*3+2] = g4[(size_t)t*3+2];
    probs_s[p] = probs[t];
}

// ---------------- grid KNN — R16-passing kernel VERBATIM ----------------
__global__ __launch_bounds__(256) void knn_grid_kernel(const float4* __restrict__ bqs,
        const int* __restrict__ oid, const int* __restrict__ csort,
        const unsigned* __restrict__ cellstart, const unsigned* __restrict__ mm,
        int* __restrict__ nbr) {
    int wave = threadIdx.x >> 6, lane = threadIdx.x & 63;
    int r = blockIdx.x * 4 + wave;
    float4 q = bqs[r];
    int myc = csort[r];
    int cx = (myc>>8)&15, cy = (myc>>4)&15, cz = myc&15;
    float mnx = decf(mm[0]), mny = decf(mm[1]), mnz = decf(mm[2]);
    float hx = (decf(mm[3]) - mnx) * (1.f/16.f);
    float hy = (decf(mm[4]) - mny) * (1.f/16.f);
    float hz = (decf(mm[5]) - mnz) * (1.f/16.f);
    float hmin = fminf(hx, fminf(hy, hz));

    float rd = INFINITY;
    int   ri = 0x7FF00000 | lane;     // distinct sentinels (orig-idx key)
    int   rk = lane;                  // sorted-idx payload
    float th = INFINITY;
    int   mi = 0x7FFFFFFF;

#define SCAN_RANGE(RS, RE)                                                          \
    for (unsigned base = (RS); base < (RE); base += 64u) {                          \
        unsigned k = base + (unsigned)lane;                                         \
        bool kv = (k < (RE));                                                       \
        float4 c4 = kv ? bqs[k] : make_float4(INFINITY,INFINITY,INFINITY,INFINITY); \
        int ov = kv ? oid[k] : 0x7FFFFFFF;                                          \
        float dot = fmaf(q.z, c4.z, fmaf(q.y, c4.y, q.x*c4.x));                     \
        float d = (q.w + c4.w) - 2.0f*dot;                                          \
        unsigned long long bal = __ballot(kv && (d <= th));                         \
        while (bal) {                                                               \
            int src = __ffsll(bal) - 1; bal &= bal - 1;                             \
            float dc = readlane_f(d, src);                                          \
            int   jc = __builtin_amdgcn_readlane(ov, src);                          \
            int   kc = (int)base + src;                                             \
            if ((dc < th) || (dc == th && jc < mi)) {                               \
                bool less = (rd < dc) || (rd == dc && ri < jc);                     \
                int pos = __popcll(__ballot(less) & 0x1FFFFFull);                   \
                float sd = __shfl_up(rd, 1);                                        \
                int   si = __shfl_up(ri, 1);                                        \
                int   sk = __shfl_up(rk, 1);                                        \
                if (lane < 21) {                                                    \
                    if (lane == pos)      { rd = dc; ri = jc; rk = kc; }            \
                    else if (lane > pos)  { rd = sd; ri = si; rk = sk; }            \
                }                                                                   \
                th = readlane_f(rd, 20);                                            \
                mi = __builtin_amdgcn_readlane(ri, 20);                             \
            }                                                                       \
        }                                                                           \
    }

#define CELL_BOUND_OK(EX, EY, EZ)                                                   \
    ({  float cl0 = fmaf((float)(EX), hx, mnx);                                     \
        float cm0 = fmaf((float)(EY), hy, mny);                                     \
        float cn0 = fmaf((float)(EZ), hz, mnz);                                     \
        float ddx = fmaxf(fmaxf(cl0 - q.x, q.x - (cl0 + hx)), 0.f);                 \
        float ddy = fmaxf(fmaxf(cm0 - q.y, q.y - (cm0 + hy)), 0.f);                 \
        float ddz = fmaxf(fmaxf(cn0 - q.z, q.z - (cn0 + hz)), 0.f);                 \
        float bnd = fmaf(ddx, ddx, fmaf(ddy, ddy, ddz*ddz));                        \
        (bnd <= th + 1e-3f); })

    // home cell first
    {
        unsigned hs = cellstart[myc], he = cellstart[myc + 1];
        SCAN_RANGE(hs, he)
    }

    for (int w = 1; w <= 15; ++w) {
        if (w == 1) {
            int i = lane;
            bool val = (i < 27) && (i != 13);
            int ii = (i < 27) ? i : 0;
            int dz = ii % 3 - 1, dy = (ii / 3) % 3 - 1, dx = ii / 9 - 1;
            int ex = cx + dx, ey = cy + dy, ez = cz + dz;
            val = val && ex >= 0 && ex < 16 && ey >= 0 && ey < 16 && ez >= 0 && ez < 16;
            int cell = (ex<<8) | (ey<<4) | ez;
            unsigned cs = 0u, ce = 0u;
            if (val) { cs = cellstart[cell]; ce = cellstart[cell+1]; }
            val = val && (cs < ce);
            if (val) val = CELL_BOUND_OK(ex, ey, ez);
            unsigned long long cm = __ballot(val);
            while (cm) {
                int cl = __ffsll(cm) - 1; cm &= cm - 1;
                unsigned s0 = (unsigned)__builtin_amdgcn_readlane((int)cs, cl);
                unsigned e0 = (unsigned)__builtin_amdgcn_readlane((int)ce, cl);
                SCAN_RANGE(s0, e0)
            }
        } else {
            int W = 2*w + 1, W2 = W*W, tot = W*W2;
            for (int b0 = 0; b0 < tot; b0 += 64) {
                int i = b0 + lane;
                bool val = (i < tot);
                int ii = val ? i : 0;
                int dz = ii % W - w, dy = (ii / W) % W - w, dx = ii / W2 - w;
                int cheb = max(abs(dx), max(abs(dy), abs(dz)));
                val = val && (cheb == w);
                int ex = cx + dx, ey = cy + dy, ez = cz + dz;
                val = val && ex >= 0 && ex < 16 && ey >= 0 && ey < 16 && ez >= 0 && ez < 16;
                int cell = (ex<<8) | (ey<<4) | ez;
                unsigned cs = 0u, ce = 0u;
                if (val) { cs = cellstart[cell]; ce = cellstart[cell+1]; }
                val = val && (cs < ce);
                if (val) val = CELL_BOUND_OK(ex, ey, ez);
                unsigned long long cm = __ballot(val);
                while (cm) {
                    int cl = __ffsll(cm) - 1; cm &= cm - 1;
                    unsigned s0 = (unsigned)__builtin_amdgcn_readlane((int)cs, cl);
                    unsigned e0 = (unsigned)__builtin_amdgcn_readlane((int)ce, cl);
                    SCAN_RANGE(s0, e0)
                }
            }
        }
        bool covered = (cx-w <= 0) && (cx+w >= 15) && (cy-w <= 0) && (cy+w >= 15)
                    && (cz-w <= 0) && (cz+w >= 15);
        if (covered) break;
        float bd = (float)w * hmin - 1e-3f;
        if (bd > 0.f && th < bd*bd) break;
    }
#undef CELL_BOUND_OK
#undef SCAN_RANGE
    if (lane >= 1 && lane < 21) nbr[r*KNN_K + lane - 1] = rk;
}

// ---------------- prep: rowsum, W1a transpose ----------------
__global__ void rowsum_kernel(const float* __restrict__ W1, float* __restrict__ rs) {
    int f = threadIdx.x;
    float s = 0.f;
    for (int c = 0; c < H; ++c) s += W1[f*137 + 9 + c];
    rs[f] = s;
}
// WA[m][c][f] = W1_m[f][c], c in [0,9)
__global__ void watrans_kernel(const float* __restrict__ W10, const float* __restrict__ W11,
                               const float* __restrict__ W12, float* __restrict__ WA) {
    int f = threadIdx.x, c = blockIdx.x, m = blockIdx.y;
    const float* W = (m == 0) ? W10 : (m == 1) ? W11 : W12;
    WA[m*9*128 + c*128 + f] = W[f*137 + c];
}

// ---------------- prep: folded inter-layer matrices M_l = W1b_{l+1} @ W2_l ----------------
// Z_{l+1} = S_l@M_l^T + v_l + geo9@W1a_{l+1}^T (two consecutive linear maps,
// no nonlinearity between: relu lives inside S). Stored interleaved like the
// old WTg: MTg[m][(c>>2)*512 + f*4 + (c&3)] = M_m[f][c].
__global__ void mfold_kernel(const float* __restrict__ W11, const float* __restrict__ W12,
                             const float* __restrict__ W20, const float* __restrict__ W21,
                             float* __restrict__ MTg) {
    int c = threadIdx.x, f = blockIdx.x, m = blockIdx.y;
    const float* W1 = m ? W12 : W11;
    const float* W2 = m ? W21 : W20;
    float acc = 0.f;
    for (int k = 0; k < 128; ++k)
        acc = fmaf(W1[f*137 + 9 + k], W2[k*128 + c], acc);
    MTg[m*16384 + (c>>2)*512 + f*4 + (c&3)] = acc;
}
// v_m[f] = K * W1b_{m+1}[f,:]·b2_m ; wf2[c] = sum_f Wf[f]*W2_2[f][c];
// cst = K*(Wf·b2_2) + bf. WV = [v0 | v1 | wf2 | cst].
__global__ void vhead_kernel(const float* __restrict__ W11, const float* __restrict__ W12,
                             const float* __restrict__ b20, const float* __restrict__ b21,
                             const float* __restrict__ b22, const float* __restrict__ W22,
                             const float* __restrict__ Wf, const float* __restrict__ bf,
                             float* __restrict__ WV) {
    int f = threadIdx.x;
    float v0 = 0.f, v1 = 0.f, w2 = 0.f;
    for (int k = 0; k < 128; ++k) {
        v0 = fmaf(W11[f*137 + 9 + k], b20[k], v0);
        v1 = fmaf(W12[f*137 + 9 + k], b21[k], v1);
        w2 = fmaf(Wf[k], W22[k*128 + f], w2);
    }
    WV[f]       = (float)KNN_K * v0;
    WV[128 + f] = (float)KNN_K * v1;
    WV[256 + f] = w2;
    if (f == 0) {
        float cacc = 0.f;
        for (int k = 0; k < 128; ++k) cacc = fmaf(Wf[k], b22[k], cacc);
        WV[384] = (float)KNN_K * cacc + bf[0];
    }
}

// ---------------- layer-0 Z ----------------
__global__ void y0_kernel(const float* __restrict__ ps, const float* __restrict__ rs,
                          const float* __restrict__ WA0, const float* __restrict__ geo_s,
                          float* __restrict__ Z) {
    int bid = xcd_swz(blockIdx.x, gridDim.x);
    int tid = bid * 256 + threadIdx.x;   // over T*H
    int t = tid >> 7, f = tid & 127;
    float acc = ps[t] * rs[f];
#pragma unroll
    for (int c = 0; c < 9; ++c)
        acc = fmaf(WA0[c*128 + f], geo_s[(size_t)t*12 + c], acc);
    Z[tid] = acc;
}

// ---------------- mid-layer fused: edge(S in LDS) -> S@M^T + v + geo@W1a^T -> Z_next ----------------
__global__ __launch_bounds__(256) void ef_mid_kernel(const float* __restrict__ Z,
                            const int* __restrict__ nbr, const float* __restrict__ b1,
                            const float* __restrict__ MTg, const float* __restrict__ v,
                            const float* __restrict__ WAn, const float* __restrict__ geo_s,
                            float* __restrict__ Znext) {
    __shared__ float Srow[4][128];
    int wave = threadIdx.x >> 6, lane = threadIdx.x & 63;
    int t0b = xcd_swz(blockIdx.x, gridDim.x) * 4;
    {
        int t = t0b + wave;
        float zsLo = Z[(size_t)t*H + lane]      + b1[lane];
        float zsHi = Z[(size_t)t*H + 64 + lane] + b1[64 + lane];
        float accLo = 0.f, accHi = 0.f;
#pragma unroll
        for (int e = 0; e < KNN_K; ++e) {
            int tg = nbr[t*KNN_K + e];
            accLo += fmaxf(zsLo - Z[(size_t)tg*H + lane],      0.f);
            accHi += fmaxf(zsHi - Z[(size_t)tg*H + 64 + lane], 0.f);
        }
        Srow[wave][lane]    = accLo;
        Srow[wave][64+lane] = accHi;
    }
    __syncthreads();
    int f = threadIdx.x & 127, half = threadIdx.x >> 7;
    float a0 = v[f], a1 = v[f];
    const int r0_ = half * 2;
#pragma unroll
    for (int c4 = 0; c4 < 32; ++c4) {
        float4 w = *(const float4*)&MTg[c4*512 + f*4];
        float4 v0 = ((const float4*)Srow[r0_+0])[c4];
        float4 v1 = ((const float4*)Srow[r0_+1])[c4];
        a0 = fmaf(w.x, v0.x, a0); a0 = fmaf(w.y, v0.y, a0);
        a0 = fmaf(w.z, v0.z, a0); a0 = fmaf(w.w, v0.w, a0);
        a1 = fmaf(w.x, v1.x, a1); a1 = fmaf(w.y, v1.y, a1);
        a1 = fmaf(w.z, v1.z, a1); a1 = fmaf(w.w, v1.w, a1);
    }
    // geo9 @ W1a_{l+1}^T epilogue
#pragma unroll
    for (int c = 0; c < 9; ++c) {
        float w = WAn[c*128 + f];
        a0 = fmaf(w, geo_s[(size_t)(t0b + r0_ + 0)*12 + c], a0);
        a1 = fmaf(w, geo_s[(size_t)(t0b + r0_ + 1)*12 + c], a1);
    }
    Znext[(size_t)(t0b+r0_+0)*H + f] = a0;
    Znext[(size_t)(t0b+r0_+1)*H + f] = a1;
}

// ---------------- last-layer fused: edge -> dot(S, wf2) + cst -> sigmoid -> out[oid] ----------------
// Head folded through W2_2: logit = S·wf2 + cst (wf2 = W2_2^T@Wf). No GEMM,
// no LDS second phase — each wave finishes its row in registers.
__global__ __launch_bounds__(256) void ef_head_kernel(const float* __restrict__ Z,
                            const int* __restrict__ nbr, const float* __restrict__ b1,
                            const float* __restrict__ WV, float* __restrict__ out,
                            const int* __restrict__ oid) {
    int wave = threadIdx.x >> 6, lane = threadIdx.x & 63;
    int t = xcd_swz(blockIdx.x, gridDim.x) * 4 + wave;
    float zsLo = Z[(size_t)t*H + lane]      + b1[lane];
    float zsHi = Z[(size_t)t*H + 64 + lane] + b1[64 + lane];
    float accLo = 0.f, accHi = 0.f;
#pragma unroll
    for (int e = 0; e < KNN_K; ++e) {
        int tg = nbr[t*KNN_K + e];
        accLo += fmaxf(zsLo - Z[(size_t)tg*H + lane],      0.f);
        accHi += fmaxf(zsHi - Z[(size_t)tg*H + 64 + lane], 0.f);
    }
    float p = fmaf(accLo, WV[256 + lane], accHi * WV[256 + 64 + lane]);
#pragma unroll
    for (int off = 32; off >= 1; off >>= 1) p += __shfl_xor(p, off);
    if (lane == 0) {
        float z = p + WV[384];
        out[oid[t]] = 1.0f / (1.0f + expf(-z));
    }
}

extern "C" void kernel_launch(void* const* d_in, const int* in_sizes, int n_in,
                              void* d_out, int out_size, void* d_ws, size_t ws_size,
                              hipStream_t stream) {
    (void)in_sizes; (void)n_in; (void)out_size; (void)ws_size;
    const float* pts   = (const float*)d_in[0];
    const int*   tris  = (const int*)d_in[1];
    const float* probs = (const float*)d_in[2];
    const float* W1[3] = {(const float*)d_in[3],  (const float*)d_in[7],  (const float*)d_in[11]};
    const float* b1[3] = {(const float*)d_in[4],  (const float*)d_in[8],  (const float*)d_in[12]};
    const float* W2[3] = {(const float*)d_in[5],  (const float*)d_in[9],  (const float*)d_in[13]};
    const float* b2[3] = {(const float*)d_in[6],  (const float*)d_in[10], (const float*)d_in[14]};
    const float* Wf = (const float*)d_in[15];
    const float* bf = (const float*)d_in[16];
    float* out = (float*)d_out;

    char* ws = (char*)d_ws;
    float*    geo  = (float*)(ws + WS_GEO);
    float4*   bq   = (float4*)(ws + WS_BQ);
    int*      nbr  = (int*)(ws + WS_NBR);
    float*    rs   = (float*)(ws + WS_RS);
    float*    MTg  = (float*)(ws + WS_MT);
    float*    WV   = (float*)(ws + WS_WV);
    unsigned* mm   = (unsigned*)(ws + WS_MM);
    unsigned* cst  = (unsigned*)(ws + WS_CSTART);
    unsigned* cptr = (unsigned*)(ws + WS_CPTR);
    unsigned* hist = (unsigned*)(ws + WS_HIST);
    int*      cid  = (int*)(ws + WS_CID);
    int*      cso  = (int*)(ws + WS_CSORT);
    int*      oid  = (int*)(ws + WS_OID);
    float4*   bqs  = (float4*)(ws + WS_BQS);
    float*    WA   = (float*)(ws + WS_WA);
    float*    ps   = (float*)(ws + WS_PS);
    float*    geos = (float*)(ws + WS_GEOS);
    float*    Za   = (float*)(ws + WS_ZA);
    float*    Zb   = (float*)(ws + WS_ZB);

    grid_init_kernel<<<16, 256, 0, stream>>>(hist, mm);
    geom_kernel<<<(T_TRI+255)/256, 256, 0, stream>>>(pts, tris, geo, bq, mm);
    cellhist_kernel<<<(T_TRI+255)/256, 256, 0, stream>>>(bq, mm, cid, hist);
    prefix_kernel<<<1, 1024, 0, stream>>>(hist, cst, cptr);
    scatter_kernel<<<(T_TRI+255)/256, 256, 0, stream>>>(bq, cid, geo, probs, cptr, bqs, oid, cso, geos, ps);
    knn_grid_kernel<<<T_TRI/4, 256, 0, stream>>>(bqs, oid, cso, cst, mm, nbr);
    rowsum_kernel<<<1, 128, 0, stream>>>(W1[0], rs);
    watrans_kernel<<<dim3(9,3), 128, 0, stream>>>(W1[0], W1[1], W1[2], WA);
    mfold_kernel<<<dim3(128,2), 128, 0, stream>>>(W1[1], W1[2], W2[0], W2[1], MTg);
    vhead_kernel<<<1, 128, 0, stream>>>(W1[1], W1[2], b2[0], b2[1], b2[2], W2[2], Wf, bf, WV);
    y0_kernel<<<(T_TRI*H)/256, 256, 0, stream>>>(ps, rs, WA, geos, Za);
    ef_mid_kernel<<<T_TRI/4, 256, 0, stream>>>(Za, nbr, b1[0], MTg,           WV,       WA + 1*9*128, geos, Zb);
    ef_mid_kernel<<<T_TRI/4, 256, 0, stream>>>(Zb, nbr, b1[1], MTg + 16384,   WV + 128, WA + 2*9*128, geos, Za);
    ef_head_kernel<<<T_TRI/4, 256, 0, stream>>>(Za, nbr, b1[2], WV, out, oid);
}

// Round 18
// 251.637 us; speedup vs baseline: 3.0731x; 1.1109x over previous
//
#include <hip/hip_runtime.h>
#include <math.h>

#define T_TRI 20000
#define KNN_K 20
#define H     128

// ---------------- workspace layout (bytes) ----------------
#define WS_GEO    0                       // 960KB (original-space geo)
#define WS_BQ     (1u<<20)                // 320KB
#define WS_NBR    (2u<<20)                // 1.6MB (sorted-space neighbor lists)
#define WS_RS     (4u<<20)                // 512B
#define WS_MT     ((4u<<20)+4096)         // MTg: 2*16384 f32 = 128KB (folded GEMMs)
#define WS_WV     ((4u<<20)+4096+(256u<<10)) // v0,v1,wf2,cst: 385 f32
#define WS_MM     (5u<<20)                // 64B
#define WS_CSTART ((5u<<20)+64)           // 4097 u32
#define WS_CPTR   ((5u<<20)+(32u<<10))    // 4096 u32
#define WS_HIST   ((5u<<20)+(64u<<10))    // 4096 u32
#define WS_CID    ((5u<<20)+(128u<<10))   // 20000 i32
#define WS_CSORT  ((5u<<20)+(256u<<10))   // 20000 i32
#define WS_OID    ((5u<<20)+(384u<<10))   // 20000 i32
#define WS_BQS    ((5u<<20)+(512u<<10))   // 320KB
#define WS_WA     ((5u<<20)+(840u<<10))   // 3*9*128 f32
#define WS_PS     (6u<<20)                // 80KB (probs_s)
#define WS_GEOS   (7u<<20)                // 960KB (sorted-space geo)
#define WS_ZB     (9u<<20)                // Z ping buffer
#define WS_ZA     (20u<<20)               // Z pong buffer

__device__ __forceinline__ float readlane_f(float v, int l) {
    return __uint_as_float(__builtin_amdgcn_readlane(__float_as_uint(v), l));
}
// order-preserving float<->uint (for atomicMin/Max on floats)
__device__ __forceinline__ unsigned encf(float f) {
    unsigned u = __float_as_uint(f);
    return (u & 0x80000000u) ? ~u : (u | 0x80000000u);
}
__device__ __forceinline__ float decf(unsigned e) {
    unsigned u = (e & 0x80000000u) ? (e & 0x7FFFFFFFu) : ~e;
    return __uint_as_float(u);
}
// m204 bijective XCD swizzle (R15/R16: aligns producer/consumer row-chunks).
__device__ __forceinline__ int xcd_swz(int bid, int nwg) {
    int q = nwg >> 3, rm = nwg & 7;
    int x = bid & 7, idx = bid >> 3;
    return (x < rm) ? x*(q+1) + idx : rm*(q+1) + (x-rm)*q + idx;
}

// ---------------- init: zero histogram, minmax sentinels ----------------
__global__ void grid_init_kernel(unsigned* __restrict__ hist, unsigned* __restrict__ mm) {
    int i = blockIdx.x * 256 + threadIdx.x;
    if (i < 4096) hist[i] = 0u;
    if (i < 3) mm[i] = 0xFFFFFFFFu;          // mins (uint-encoded)
    if (i >= 3 && i < 6) mm[i] = 0u;         // maxs
}

// ---------------- geometry (+ bary AABB via wave-reduced atomics) ----------------
__global__ void geom_kernel(const float* __restrict__ pts, const int* __restrict__ tris,
                            float* __restrict__ geo, float4* __restrict__ bq,
                            unsigned* __restrict__ mm) {
    int t = blockIdx.x * blockDim.x + threadIdx.x;
    int lane = threadIdx.x & 63;
    bool act = (t < T_TRI);
    int tt = act ? t : 0;
    int i0 = tris[3*tt], i1 = tris[3*tt+1], i2 = tris[3*tt+2];
    float ax = pts[3*i0], ay = pts[3*i0+1], az = pts[3*i0+2];
    float bx = pts[3*i1], by = pts[3*i1+1], bz = pts[3*i1+2];
    float cx = pts[3*i2], cy = pts[3*i2+1], cz = pts[3*i2+2];
    float e0x = ax-bx, e0y = ay-by, e0z = az-bz;   // e_ij
    float e1x = ax-cx, e1y = ay-cy, e1z = az-cz;   // e_ik
    float e2x = bx-cx, e2y = by-cy, e2z = bz-cz;   // e_jk
    float mnx = fminf(fminf(e0x,e1x),e2x), mny = fminf(fminf(e0y,e1y),e2y), mnz = fminf(fminf(e0z,e1z),e2z);
    float mxx = fmaxf(fmaxf(e0x,e1x),e2x), mxy = fmaxf(fmaxf(e0y,e1y),e2y), mxz = fmaxf(fmaxf(e0z,e1z),e2z);
    float gx = (ax+bx+cx)*(1.0f/3.0f), gy = (ay+by+cy)*(1.0f/3.0f), gz = (az+bz+cz)*(1.0f/3.0f);
    float sq = (gx*gx + gy*gy) + gz*gz;
    if (act) {
        float* g = geo + (size_t)t*12;
        g[0]=mnx; g[1]=mny; g[2]=mnz; g[3]=mxx; g[4]=mxy; g[5]=mxz;
        g[6]=gx;  g[7]=gy;  g[8]=gz;  g[9]=0.f; g[10]=0.f; g[11]=0.f;
        bq[t] = make_float4(gx, gy, gz, sq);
    }
    unsigned n0 = act ? encf(gx) : 0xFFFFFFFFu;
    unsigned n1 = act ? encf(gy) : 0xFFFFFFFFu;
    unsigned n2 = act ? encf(gz) : 0xFFFFFFFFu;
    unsigned x0 = act ? encf(gx) : 0u;
    unsigned x1 = act ? encf(gy) : 0u;
    unsigned x2 = act ? encf(gz) : 0u;
#pragma unroll
    for (int off = 32; off >= 1; off >>= 1) {
        n0 = min(n0, (unsigned)__shfl_xor((int)n0, off));
        n1 = min(n1, (unsigned)__shfl_xor((int)n1, off));
        n2 = min(n2, (unsigned)__shfl_xor((int)n2, off));
        x0 = max(x0, (unsigned)__shfl_xor((int)x0, off));
        x1 = max(x1, (unsigned)__shfl_xor((int)x1, off));
        x2 = max(x2, (unsigned)__shfl_xor((int)x2, off));
    }
    if (lane == 0) {
        atomicMin(&mm[0], n0); atomicMin(&mm[1], n1); atomicMin(&mm[2], n2);
        atomicMax(&mm[3], x0); atomicMax(&mm[4], x1); atomicMax(&mm[5], x2);
    }
}

// ---------------- cell assignment + histogram ----------------
__global__ void cellhist_kernel(const float4* __restrict__ bq, const unsigned* __restrict__ mm,
                                int* __restrict__ cellid, unsigned* __restrict__ hist) {
    int t = blockIdx.x * 256 + threadIdx.x;
    if (t >= T_TRI) return;
    float mnx = decf(mm[0]), mny = decf(mm[1]), mnz = decf(mm[2]);
    float mxx = decf(mm[3]), mxy = decf(mm[4]), mxz = decf(mm[5]);
    float ihx = 16.f / fmaxf(mxx-mnx, 1e-30f);
    float ihy = 16.f / fmaxf(mxy-mny, 1e-30f);
    float ihz = 16.f / fmaxf(mxz-mnz, 1e-30f);
    float4 b = bq[t];
    int ix = min(15, max(0, (int)((b.x-mnx)*ihx)));
    int iy = min(15, max(0, (int)((b.y-mny)*ihy)));
    int iz = min(15, max(0, (int)((b.z-mnz)*ihz)));
    int c = (ix<<8) | (iy<<4) | iz;
    cellid[t] = c;
    atomicAdd(&hist[c], 1u);
}

// ---------------- exclusive prefix over 4096 cells (1 block) ----------------
__global__ __launch_bounds__(1024) void prefix_kernel(const unsigned* __restrict__ hist,
                                                      unsigned* __restrict__ cellstart,
                                                      unsigned* __restrict__ cellptr) {
    __shared__ unsigned sbuf[1024];
    int tid = threadIdx.x;
    uint4 v = ((const uint4*)hist)[tid];
    unsigned mysum = v.x + v.y + v.z + v.w;
    sbuf[tid] = mysum;
    __syncthreads();
    for (int off = 1; off < 1024; off <<= 1) {
        unsigned add = (tid >= off) ? sbuf[tid - off] : 0u;
        __syncthreads();
        sbuf[tid] += add;
        __syncthreads();
    }
    unsigned excl = sbuf[tid] - mysum;
    unsigned p0 = excl, p1 = p0 + v.x, p2 = p1 + v.y, p3 = p2 + v.z;
    cellstart[4*tid+0] = p0; cellstart[4*tid+1] = p1;
    cellstart[4*tid+2] = p2; cellstart[4*tid+3] = p3;
    cellptr[4*tid+0] = p0; cellptr[4*tid+1] = p1;
    cellptr[4*tid+2] = p2; cellptr[4*tid+3] = p3;
    if (tid == 1023) cellstart[4096] = p3 + v.w;
}

// ---------------- scatter into cell-sorted order (+ relabeled geo/probs) ----------------
__global__ void scatter_kernel(const float4* __restrict__ bq, const int* __restrict__ cellid,
                               const float* __restrict__ geo, const float* __restrict__ probs,
                               unsigned* __restrict__ cellptr, float4* __restrict__ bqs,
                               int* __restrict__ oid, int* __restrict__ csort,
                               float* __restrict__ geo_s, float* __restrict__ probs_s) {
    int t = blockIdx.x * 256 + threadIdx.x;
    if (t >= T_TRI) return;
    int c = cellid[t];
    unsigned p = atomicAdd(&cellptr[c], 1u);
    bqs[p] = bq[t];
    oid[p]  = t;
    csort[p] = c;
    const float4* g4 = (const float4*)geo;
    float4* g4s = (float4*)geo_s;
    g4s[(size_t)p*3+0] = g4[(size_t)t*3+0];
    g4s[(size_t)p*3+1] = g4[(size_t)t*3+1];
    g4s[(size_t)p*3+2] = g4[(size_t)t*3+2];
    probs_s[p] = probs[t];
}

// ---------------- grid KNN: bitonic first home batch + bound-pruned windows ----------------
// R17 structure with ONE change: the home cell's first <=64 candidates are
// bitonic-sorted (21 lane-parallel compare-exchange stages, exact (d,origidx)
// lex key, sorted-index payload carried) to seed the list + theta, replacing
// the serial theta=INF warm-up drain (~40 sequential insert events). The
// running bottom-21 under the strict total order is unchanged -> identical
// selection. Invalid lanes get explicit d=INF + distinct sentinel idx AFTER
// the fma (NaN keys would break the sort network; the prescreen tolerated
// them, the sort doesn't). Everything else byte-identical to R16/R17.
__global__ __launch_bounds__(256) void knn_grid_kernel(const float4* __restrict__ bqs,
        const int* __restrict__ oid, const int* __restrict__ csort,
        const unsigned* __restrict__ cellstart, const unsigned* __restrict__ mm,
        int* __restrict__ nbr) {
    int wave = threadIdx.x >> 6, lane = threadIdx.x & 63;
    int r = blockIdx.x * 4 + wave;
    float4 q = bqs[r];
    int myc = csort[r];
    int cx = (myc>>8)&15, cy = (myc>>4)&15, cz = myc&15;
    float mnx = decf(mm[0]), mny = decf(mm[1]), mnz = decf(mm[2]);
    float hx = (decf(mm[3]) - mnx) * (1.f/16.f);
    float hy = (decf(mm[4]) - mny) * (1.f/16.f);
    float hz = (decf(mm[5]) - mnz) * (1.f/16.f);
    float hmin = fminf(hx, fminf(hy, hz));

    float rd = INFINITY;
    int   ri = 0x7FF00000 | lane;     // distinct sentinels (orig-idx key)
    int   rk = lane;                  // sorted-idx payload
    float th = INFINITY;
    int   mi = 0x7FFFFFFF;

#define SCAN_RANGE(RS, RE)                                                          \
    for (unsigned base = (RS); base < (RE); base += 64u) {                          \
        unsigned k = base + (unsigned)lane;                                         \
        bool kv = (k < (RE));                                                       \
        float4 c4 = kv ? bqs[k] : make_float4(INFINITY,INFINITY,INFINITY,INFINITY); \
        int ov = kv ? oid[k] : 0x7FFFFFFF;                                          \
        float dot = fmaf(q.z, c4.z, fmaf(q.y, c4.y, q.x*c4.x));                     \
        float d = (q.w + c4.w) - 2.0f*dot;                                          \
        unsigned long long bal = __ballot(kv && (d <= th));                         \
        while (bal) {                                                               \
            int src = __ffsll(bal) - 1; bal &= bal - 1;                             \
            float dc = readlane_f(d, src);                                          \
            int   jc = __builtin_amdgcn_readlane(ov, src);                          \
            int   kc = (int)base + src;                                             \
            if ((dc < th) || (dc == th && jc < mi)) {                               \
                bool less = (rd < dc) || (rd == dc && ri < jc);                     \
                int pos = __popcll(__ballot(less) & 0x1FFFFFull);                   \
                float sd = __shfl_up(rd, 1);                                        \
                int   si = __shfl_up(ri, 1);                                        \
                int   sk = __shfl_up(rk, 1);                                        \
                if (lane < 21) {                                                    \
                    if (lane == pos)      { rd = dc; ri = jc; rk = kc; }            \
                    else if (lane > pos)  { rd = sd; ri = si; rk = sk; }            \
                }                                                                   \
                th = readlane_f(rd, 20);                                            \
                mi = __builtin_amdgcn_readlane(ri, 20);                             \
            }                                                                       \
        }                                                                           \
    }

#define CELL_BOUND_OK(EX, EY, EZ)                                                   \
    ({  float cl0 = fmaf((float)(EX), hx, mnx);                                     \
        float cm0 = fmaf((float)(EY), hy, mny);                                     \
        float cn0 = fmaf((float)(EZ), hz, mnz);                                     \
        float ddx = fmaxf(fmaxf(cl0 - q.x, q.x - (cl0 + hx)), 0.f);                 \
        float ddy = fmaxf(fmaxf(cm0 - q.y, q.y - (cm0 + hy)), 0.f);                 \
        float ddz = fmaxf(fmaxf(cn0 - q.z, q.z - (cn0 + hz)), 0.f);                 \
        float bnd = fmaf(ddx, ddx, fmaf(ddy, ddy, ddz*ddz));                        \
        (bnd <= th + 1e-3f); })

    // ---- home cell: first batch via bitonic sort (warm-up elimination) ----
    {
        unsigned hs = cellstart[myc], he = cellstart[myc + 1];
        unsigned k64 = hs + (unsigned)lane;
        bool kv = (k64 < he);
        float4 c4 = kv ? bqs[k64] : make_float4(INFINITY,INFINITY,INFINITY,INFINITY);
        float dot = fmaf(q.z, c4.z, fmaf(q.y, c4.y, q.x*c4.x));
        float d = (q.w + c4.w) - 2.0f*dot;
        int   jx = kv ? oid[k64] : (0x7FF00000 | lane);
        int   kc = kv ? (int)k64 : 0;
        if (!kv) d = INFINITY;          // kill NaN/INF garbage: sort needs clean keys
#pragma unroll
        for (int kk = 2; kk <= 64; kk <<= 1) {
#pragma unroll
            for (int jj = kk >> 1; jj >= 1; jj >>= 1) {
                float od = __shfl_xor(d, jj);
                int   oj = __shfl_xor(jx, jj);
                int   ok = __shfl_xor(kc, jj);
                bool up    = ((lane & kk) == 0);
                bool lower = ((lane & jj) == 0);
                bool less  = (d < od) || (d == od && jx < oj);
                bool keep  = ((lower == up) ? less : !less);
                d = keep ? d : od; jx = keep ? jx : oj; kc = keep ? kc : ok;
            }
        }
        rd = d; ri = jx; rk = kc;       // lane l = rank-l (junk for l>20, harmless)
        th = readlane_f(rd, 20);
        mi = __builtin_amdgcn_readlane(ri, 20);
        if (hs + 64u < he) { SCAN_RANGE(hs + 64u, he) }
    }

    for (int w = 1; w <= 15; ++w) {
        if (w == 1) {
            int i = lane;
            bool val = (i < 27) && (i != 13);
            int ii = (i < 27) ? i : 0;
            int dz = ii % 3 - 1, dy = (ii / 3) % 3 - 1, dx = ii / 9 - 1;
            int ex = cx + dx, ey = cy + dy, ez = cz + dz;
            val = val && ex >= 0 && ex < 16 && ey >= 0 && ey < 16 && ez >= 0 && ez < 16;
            int cell = (ex<<8) | (ey<<4) | ez;
            unsigned cs = 0u, ce = 0u;
            if (val) { cs = cellstart[cell]; ce = cellstart[cell+1]; }
            val = val && (cs < ce);
            if (val) val = CELL_BOUND_OK(ex, ey, ez);
            unsigned long long cm = __ballot(val);
            while (cm) {
                int cl = __ffsll(cm) - 1; cm &= cm - 1;
                unsigned s0 = (unsigned)__builtin_amdgcn_readlane((int)cs, cl);
                unsigned e0 = (unsigned)__builtin_amdgcn_readlane((int)ce, cl);
                SCAN_RANGE(s0, e0)
            }
        } else {
            int W = 2*w + 1, W2 = W*W, tot = W*W2;
            for (int b0 = 0; b0 < tot; b0 += 64) {
                int i = b0 + lane;
                bool val = (i < tot);
                int ii = val ? i : 0;
                int dz = ii % W - w, dy = (ii / W) % W - w, dx = ii / W2 - w;
                int cheb = max(abs(dx), max(abs(dy), abs(dz)));
                val = val && (cheb == w);
                int ex = cx + dx, ey = cy + dy, ez = cz + dz;
                val = val && ex >= 0 && ex < 16 && ey >= 0 && ey < 16 && ez >= 0 && ez < 16;
                int cell = (ex<<8) | (ey<<4) | ez;
                unsigned cs = 0u, ce = 0u;
                if (val) { cs = cellstart[cell]; ce = cellstart[cell+1]; }
                val = val && (cs < ce);
                if (val) val = CELL_BOUND_OK(ex, ey, ez);
                unsigned long long cm = __ballot(val);
                while (cm) {
                    int cl = __ffsll(cm) - 1; cm &= cm - 1;
                    unsigned s0 = (unsigned)__builtin_amdgcn_readlane((int)cs, cl);
                    unsigned e0 = (unsigned)__builtin_amdgcn_readlane((int)ce, cl);
                    SCAN_RANGE(s0, e0)
                }
            }
        }
        bool covered = (cx-w <= 0) && (cx+w >= 15) && (cy-w <= 0) && (cy+w >= 15)
                    && (cz-w <= 0) && (cz+w >= 15);
        if (covered) break;
        float bd = (float)w * hmin - 1e-3f;
        if (bd > 0.f && th < bd*bd) break;
    }
#undef CELL_BOUND_OK
#undef SCAN_RANGE
    if (lane >= 1 && lane < 21) nbr[r*KNN_K + lane - 1] = rk;
}

// ---------------- prep: rowsum + W1a transpose + folded vectors/head (1 launch) ----------------
__global__ void prep_kernel(const float* __restrict__ W10, const float* __restrict__ W11,
                            const float* __restrict__ W12,
                            const float* __restrict__ b20, const float* __restrict__ b21,
                            const float* __restrict__ b22, const float* __restrict__ W22,
                            const float* __restrict__ Wf, const float* __restrict__ bf,
                            float* __restrict__ rs, float* __restrict__ WA,
                            float* __restrict__ WV) {
    int f = threadIdx.x;   // 128
    // rowsum of W1b_0
    float s = 0.f;
    for (int c = 0; c < H; ++c) s += W10[f*137 + 9 + c];
    rs[f] = s;
    // WA[m][c][f] = W1_m[f][c]
#pragma unroll
    for (int c = 0; c < 9; ++c) {
        WA[0*1152 + c*128 + f] = W10[f*137 + c];
        WA[1*1152 + c*128 + f] = W11[f*137 + c];
        WA[2*1152 + c*128 + f] = W12[f*137 + c];
    }
    // v_m[f] = K * W1b_{m+1}[f,:]·b2_m ; wf2[f] = sum_k Wf[k]*W2_2[k][f]
    float v0 = 0.f, v1 = 0.f, w2 = 0.f;
    for (int k = 0; k < 128; ++k) {
        v0 = fmaf(W11[f*137 + 9 + k], b20[k], v0);
        v1 = fmaf(W12[f*137 + 9 + k], b21[k], v1);
        w2 = fmaf(Wf[k], W22[k*128 + f], w2);
    }
    WV[f]       = (float)KNN_K * v0;
    WV[128 + f] = (float)KNN_K * v1;
    WV[256 + f] = w2;
    if (f == 0) {
        float cacc = 0.f;
        for (int k = 0; k < 128; ++k) cacc = fmaf(Wf[k], b22[k], cacc);
        WV[384] = (float)KNN_K * cacc + bf[0];
    }
}

// ---------------- prep: folded inter-layer matrices M_l = W1b_{l+1} @ W2_l ----------------
__global__ void mfold_kernel(const float* __restrict__ W11, const float* __restrict__ W12,
                             const float* __restrict__ W20, const float* __restrict__ W21,
                             float* __restrict__ MTg) {
    int c = threadIdx.x, f = blockIdx.x, m = blockIdx.y;
    const float* W1 = m ? W12 : W11;
    const float* W2 = m ? W21 : W20;
    float acc = 0.f;
    for (int k = 0; k < 128; ++k)
        acc = fmaf(W1[f*137 + 9 + k], W2[k*128 + c], acc);
    MTg[m*16384 + (c>>2)*512 + f*4 + (c&3)] = acc;
}

// ---------------- layer-0 Z ----------------
__global__ void y0_kernel(const float* __restrict__ ps, const float* __restrict__ rs,
                          const float* __restrict__ WA0, const float* __restrict__ geo_s,
                          float* __restrict__ Z) {
    int bid = xcd_swz(blockIdx.x, gridDim.x);
    int tid = bid * 256 + threadIdx.x;   // over T*H
    int t = tid >> 7, f = tid & 127;
    float acc = ps[t] * rs[f];
#pragma unroll
    for (int c = 0; c < 9; ++c)
        acc = fmaf(WA0[c*128 + f], geo_s[(size_t)t*12 + c], acc);
    Z[tid] = acc;
}

// ---------------- mid-layer fused: 8 rows / 512-thread block ----------------
// Edge phase keeps 1 row/wave (20000 gather-waves, R8 lesson); GEMM phase
// covers 8 rows per block -> per-block MTg L2 re-reads amortized 2x vs R17.
__global__ __launch_bounds__(512) void ef_mid_kernel(const float* __restrict__ Z,
                            const int* __restrict__ nbr, const float* __restrict__ b1,
                            const float* __restrict__ MTg, const float* __restrict__ v,
                            const float* __restrict__ WAn, const float* __restrict__ geo_s,
                            float* __restrict__ Znext) {
    __shared__ float Srow[8][128];
    int wave = threadIdx.x >> 6, lane = threadIdx.x & 63;
    int t0b = xcd_swz(blockIdx.x, gridDim.x) * 8;
    {
        int t = t0b + wave;
        float zsLo = Z[(size_t)t*H + lane]      + b1[lane];
        float zsHi = Z[(size_t)t*H + 64 + lane] + b1[64 + lane];
        float accLo = 0.f, accHi = 0.f;
#pragma unroll
        for (int e = 0; e < KNN_K; ++e) {
            int tg = nbr[t*KNN_K + e];
            accLo += fmaxf(zsLo - Z[(size_t)tg*H + lane],      0.f);
            accHi += fmaxf(zsHi - Z[(size_t)tg*H + 64 + lane], 0.f);
        }
        Srow[wave][lane]    = accLo;
        Srow[wave][64+lane] = accHi;
    }
    __syncthreads();
    int f = threadIdx.x & 127, grp = threadIdx.x >> 7;   // 4 groups x 2 rows
    float a0 = v[f], a1 = v[f];
    const int r0_ = grp * 2;
#pragma unroll
    for (int c4 = 0; c4 < 32; ++c4) {
        float4 w = *(const float4*)&MTg[c4*512 + f*4];
        float4 v0 = ((const float4*)Srow[r0_+0])[c4];
        float4 v1 = ((const float4*)Srow[r0_+1])[c4];
        a0 = fmaf(w.x, v0.x, a0); a0 = fmaf(w.y, v0.y, a0);
        a0 = fmaf(w.z, v0.z, a0); a0 = fmaf(w.w, v0.w, a0);
        a1 = fmaf(w.x, v1.x, a1); a1 = fmaf(w.y, v1.y, a1);
        a1 = fmaf(w.z, v1.z, a1); a1 = fmaf(w.w, v1.w, a1);
    }
#pragma unroll
    for (int c = 0; c < 9; ++c) {
        float w = WAn[c*128 + f];
        a0 = fmaf(w, geo_s[(size_t)(t0b + r0_ + 0)*12 + c], a0);
        a1 = fmaf(w, geo_s[(size_t)(t0b + r0_ + 1)*12 + c], a1);
    }
    Znext[(size_t)(t0b+r0_+0)*H + f] = a0;
    Znext[(size_t)(t0b+r0_+1)*H + f] = a1;
}

// ---------------- last-layer fused: edge -> dot(S, wf2) + cst -> sigmoid ----------------
__global__ __launch_bounds__(256) void ef_head_kernel(const float* __restrict__ Z,
                            const int* __restrict__ nbr, const float* __restrict__ b1,
                            const float* __restrict__ WV, float* __restrict__ out,
                            const int* __restrict__ oid) {
    int wave = threadIdx.x >> 6, lane = threadIdx.x & 63;
    int t = xcd_swz(blockIdx.x, gridDim.x) * 4 + wave;
    float zsLo = Z[(size_t)t*H + lane]      + b1[lane];
    float zsHi = Z[(size_t)t*H + 64 + lane] + b1[64 + lane];
    float accLo = 0.f, accHi = 0.f;
#pragma unroll
    for (int e = 0; e < KNN_K; ++e) {
        int tg = nbr[t*KNN_K + e];
        accLo += fmaxf(zsLo - Z[(size_t)tg*H + lane],      0.f);
        accHi += fmaxf(zsHi - Z[(size_t)tg*H + 64 + lane], 0.f);
    }
    float p = fmaf(accLo, WV[256 + lane], accHi * WV[256 + 64 + lane]);
#pragma unroll
    for (int off = 32; off >= 1; off >>= 1) p += __shfl_xor(p, off);
    if (lane == 0) {
        float z = p + WV[384];
        out[oid[t]] = 1.0f / (1.0f + expf(-z));
    }
}

extern "C" void kernel_launch(void* const* d_in, const int* in_sizes, int n_in,
                              void* d_out, int out_size, void* d_ws, size_t ws_size,
                              hipStream_t stream) {
    (void)in_sizes; (void)n_in; (void)out_size; (void)ws_size;
    const float* pts   = (const float*)d_in[0];
    const int*   tris  = (const int*)d_in[1];
    const float* probs = (const float*)d_in[2];
    const float* W1[3] = {(const float*)d_in[3],  (const float*)d_in[7],  (const float*)d_in[11]};
    const float* b1[3] = {(const float*)d_in[4],  (const float*)d_in[8],  (const float*)d_in[12]};
    const float* W2[3] = {(const float*)d_in[5],  (const float*)d_in[9],  (const float*)d_in[13]};
    const float* b2[3] = {(const float*)d_in[6],  (const float*)d_in[10], (const float*)d_in[14]};
    const float* Wf = (const float*)d_in[15];
    const float* bf = (const float*)d_in[16];
    float* out = (float*)d_out;

    char* ws = (char*)d_ws;
    float*    geo  = (float*)(ws + WS_GEO);
    float4*   bq   = (float4*)(ws + WS_BQ);
    int*      nbr  = (int*)(ws + WS_NBR);
    float*    rs   = (float*)(ws + WS_RS);
    float*    MTg  = (float*)(ws + WS_MT);
    float*    WV   = (float*)(ws + WS_WV);
    unsigned* mm   = (unsigned*)(ws + WS_MM);
    unsigned* cst  = (unsigned*)(ws + WS_CSTART);
    unsigned* cptr = (unsigned*)(ws + WS_CPTR);
    unsigned* hist = (unsigned*)(ws + WS_HIST);
    int*      cid  = (int*)(ws + WS_CID);
    int*      cso  = (int*)(ws + WS_CSORT);
    int*      oid  = (int*)(ws + WS_OID);
    float4*   bqs  = (float4*)(ws + WS_BQS);
    float*    WA   = (float*)(ws + WS_WA);
    float*    ps   = (float*)(ws + WS_PS);
    float*    geos = (float*)(ws + WS_GEOS);
    float*    Za   = (float*)(ws + WS_ZA);
    float*    Zb   = (float*)(ws + WS_ZB);

    grid_init_kernel<<<16, 256, 0, stream>>>(hist, mm);
    geom_kernel<<<(T_TRI+255)/256, 256, 0, stream>>>(pts, tris, geo, bq, mm);
    cellhist_kernel<<<(T_TRI+255)/256, 256, 0, stream>>>(bq, mm, cid, hist);
    prefix_kernel<<<1, 1024, 0, stream>>>(hist, cst, cptr);
    scatter_kernel<<<(T_TRI+255)/256, 256, 0, stream>>>(bq, cid, geo, probs, cptr, bqs, oid, cso, geos, ps);
    knn_grid_kernel<<<T_TRI/4, 256, 0, stream>>>(bqs, oid, cso, cst, mm, nbr);
    prep_kernel<<<1, 128, 0, stream>>>(W1[0], W1[1], W1[2], b2[0], b2[1], b2[2], W2[2], Wf, bf, rs, WA, WV);
    mfold_kernel<<<dim3(128,2), 128, 0, stream>>>(W1[1], W1[2], W2[0], W2[1], MTg);
    y0_kernel<<<(T_TRI*H)/256, 256, 0, stream>>>(ps, rs, WA, geos, Za);
    ef_mid_kernel<<<T_TRI/8, 512, 0, stream>>>(Za, nbr, b1[0], MTg,         WV,       WA + 1*1152, geos, Zb);
    ef_mid_kernel<<<T_TRI/8, 512, 0, stream>>>(Zb, nbr, b1[1], MTg + 16384, WV + 128, WA + 2*1152, geos, Za);
    ef_head_kernel<<<T_TRI/4, 256, 0, stream>>>(Za, nbr, b1[2], WV, out, oid);
}